// Round 2
// baseline (1152.788 us; speedup 1.0000x reference)
//
#include <hip/hip_runtime.h>

#define NNODES 100000
#define NEDGES 1600000
#define NGRAPHS 2000
#define HID 256
#define OUTD 128
#define NCLS 60
#define BN_EPS 1e-5f
#define NROWBLK 1563   // ceil(NNODES/64)
#define NSCANBLK 98    // ceil(NNODES/1024)
#define REDBLK 32

// ---------------- utility ----------------
__global__ void k_zero_int(int* __restrict__ p, int n) {
    int i = blockIdx.x * blockDim.x + threadIdx.x;
    if (i < n) p[i] = 0;
}

// ---------------- degrees ----------------
__global__ void k_deg(const int* __restrict__ src, const int* __restrict__ dst,
                      int* __restrict__ dout, int* __restrict__ din) {
    int e = blockIdx.x * blockDim.x + threadIdx.x;
    if (e < NEDGES) {
        atomicAdd(&dout[src[e]], 1);
        atomicAdd(&din[dst[e]], 1);
    }
}

__global__ void k_isqrt(const int* __restrict__ dout, const int* __restrict__ din,
                        float* __restrict__ dos, float* __restrict__ dis) {
    int i = blockIdx.x * blockDim.x + threadIdx.x;
    if (i < NNODES) {
        int a = dout[i], b = din[i];
        dos[i] = a > 0 ? 1.0f / sqrtf((float)a) : 0.0f;
        dis[i] = b > 0 ? 1.0f / sqrtf((float)b) : 0.0f;
    }
}

// ---------------- hierarchical exclusive scan of din -> row_ptr / cursor ----------
__global__ void k_blk_sum(const int* __restrict__ deg, int* __restrict__ bsum) {
    __shared__ int red[256];
    int blk = blockIdx.x, tid = threadIdx.x;
    int base = blk * 1024;
    int s = 0;
#pragma unroll
    for (int j = 0; j < 4; ++j) {
        int i = base + tid + j * 256;
        if (i < NNODES) s += deg[i];
    }
    red[tid] = s;
    __syncthreads();
    for (int off = 128; off > 0; off >>= 1) {
        if (tid < off) red[tid] += red[tid + off];
        __syncthreads();
    }
    if (tid == 0) bsum[blk] = red[0];
}

__global__ void k_scan_bsum(int* __restrict__ bsum) {
    if (threadIdx.x == 0) {
        int acc = 0;
        for (int i = 0; i < NSCANBLK; ++i) { int v = bsum[i]; bsum[i] = acc; acc += v; }
    }
}

__global__ void k_scan_local(const int* __restrict__ deg, const int* __restrict__ bsum,
                             int* __restrict__ row_ptr, int* __restrict__ cursor) {
    __shared__ int buf[1024];
    int blk = blockIdx.x, tid = threadIdx.x;
    int i = blk * 1024 + tid;
    int v = (i < NNODES) ? deg[i] : 0;
    buf[tid] = v;
    __syncthreads();
    for (int off = 1; off < 1024; off <<= 1) {
        int t = (tid >= off) ? buf[tid - off] : 0;
        __syncthreads();
        buf[tid] += t;
        __syncthreads();
    }
    int inc = buf[tid] + bsum[blk];
    if (i < NNODES) { row_ptr[i + 1] = inc; cursor[i] = inc - v; }
    if (i == 0) row_ptr[0] = 0;
}

__global__ void k_scatter(const int* __restrict__ src, const int* __restrict__ dst,
                          const float* __restrict__ dos, int* __restrict__ cursor,
                          int* __restrict__ csr_src, float* __restrict__ csr_w) {
    int e = blockIdx.x * blockDim.x + threadIdx.x;
    if (e < NEDGES) {
        int s = src[e], d = dst[e];
        int pos = atomicAdd(&cursor[d], 1);
        csr_src[pos] = s;
        csr_w[pos] = dos[s];
    }
}

// ---------------- M1 = W_emb @ Wc1 (6x256), v1 = b_emb @ Wc1 (256) ----------------
__global__ void k_small_mm(const float* __restrict__ Wemb, const float* __restrict__ bemb,
                           const float* __restrict__ Wc1, float* __restrict__ M1,
                           float* __restrict__ v1) {
    int c = threadIdx.x;
    int bi = blockIdx.x;
    float acc = 0.f;
    if (bi < 6) {
        for (int k = 0; k < HID; ++k) acc = fmaf(Wemb[bi * HID + k], Wc1[k * HID + c], acc);
        M1[bi * HID + c] = acc;
    } else {
        for (int k = 0; k < HID; ++k) acc = fmaf(bemb[k], Wc1[k * HID + c], acc);
        v1[c] = acc;
    }
}

// ---------------- 6-dim edge aggregation (for collapsed layer-1 conv) ----------------
__global__ void k_agg6(const int* __restrict__ row_ptr, const int* __restrict__ csr_src,
                       const float* __restrict__ csr_w, const float* __restrict__ nf,
                       float* __restrict__ t6, float* __restrict__ u1) {
    int n = blockIdx.x * blockDim.x + threadIdx.x;
    if (n >= NNODES) return;
    float a0 = 0, a1 = 0, a2 = 0, a3 = 0, a4 = 0, a5 = 0, au = 0;
    int s = row_ptr[n], e = row_ptr[n + 1];
    for (int idx = s; idx < e; ++idx) {
        int sn = csr_src[idx];
        float w = csr_w[idx];
        const float* p = nf + (size_t)sn * 6;
        a0 = fmaf(w, p[0], a0); a1 = fmaf(w, p[1], a1); a2 = fmaf(w, p[2], a2);
        a3 = fmaf(w, p[3], a3); a4 = fmaf(w, p[4], a4); a5 = fmaf(w, p[5], a5);
        au += w;
    }
    float* t = t6 + (size_t)n * 6;
    t[0] = a0; t[1] = a1; t[2] = a2; t[3] = a3; t[4] = a4; t[5] = a5;
    u1[n] = au;
}

// ---------------- fused layer 1: h_pre1 = nf@Wemb + bemb + din*(t@M1 + u*v1) + bc1
//                  + per-block BN partial stats ----------------
__global__ __launch_bounds__(256) void k_layer1(
    const float* __restrict__ nf, const float* __restrict__ Wemb, const float* __restrict__ bemb,
    const float* __restrict__ M1, const float* __restrict__ v1, const float* __restrict__ bc1,
    const float* __restrict__ t6, const float* __restrict__ u1, const float* __restrict__ dis,
    float* __restrict__ H, float* __restrict__ psum, float* __restrict__ psq) {
    __shared__ float s_nf[64][6];
    __shared__ float s_t6[64][6];
    __shared__ float s_u[64];
    __shared__ float s_r[64];
    int blk = blockIdx.x;
    int n0 = blk * 64;
    int tid = threadIdx.x;
    // FIX R1: 384 shared entries, 256 threads -> strided loop (was if(tid<384): rows 42..63 garbage)
    for (int t = tid; t < 384; t += 256) {
        int nl = t / 6, i = t % 6;
        int n = n0 + nl;
        s_nf[nl][i] = (n < NNODES) ? nf[(size_t)n * 6 + i] : 0.f;
        s_t6[nl][i] = (n < NNODES) ? t6[(size_t)n * 6 + i] : 0.f;
    }
    if (tid < 64) {
        int n = n0 + tid;
        s_u[tid] = (n < NNODES) ? u1[n] : 0.f;
        s_r[tid] = (n < NNODES) ? dis[n] : 0.f;
    }
    int c = tid;
    float wc[6], mc[6];
#pragma unroll
    for (int i = 0; i < 6; ++i) { wc[i] = Wemb[i * HID + c]; mc[i] = M1[i * HID + c]; }
    float v1c = v1[c];
    float bsum = bemb[c] + bc1[c];
    __syncthreads();
    float ps = 0.f, pq = 0.f;
    int nmax = min(64, NNODES - n0);
    for (int nl = 0; nl < nmax; ++nl) {
        float nfd = 0.f, td = 0.f;
#pragma unroll
        for (int i = 0; i < 6; ++i) {
            nfd = fmaf(s_nf[nl][i], wc[i], nfd);
            td = fmaf(s_t6[nl][i], mc[i], td);
        }
        float val = nfd + s_r[nl] * (td + s_u[nl] * v1c) + bsum;
        H[(size_t)(n0 + nl) * HID + c] = val;
        ps += val;
        pq = fmaf(val, val, pq);
    }
    psum[blk * HID + c] = ps;
    psq[blk * HID + c] = pq;
}

// ---------------- BN two-stage reduce -> scale/shift ----------------
__global__ void k_bn_part(const float* __restrict__ psum, const float* __restrict__ psq,
                          double* __restrict__ tmp) {
    int c = threadIdx.x;   // 256
    int s = blockIdx.x;    // REDBLK
    double a = 0.0, b = 0.0;
    for (int bb = s; bb < NROWBLK; bb += REDBLK) {
        a += psum[bb * HID + c];
        b += psq[bb * HID + c];
    }
    tmp[s * HID + c] = a;
    tmp[(REDBLK + s) * HID + c] = b;
}

__global__ void k_bn_final(const double* __restrict__ tmp, const float* __restrict__ g,
                           const float* __restrict__ be, float* __restrict__ scale,
                           float* __restrict__ shift) {
    int c = threadIdx.x;
    double s = 0.0, q = 0.0;
    for (int i = 0; i < REDBLK; ++i) { s += tmp[i * HID + c]; q += tmp[(REDBLK + i) * HID + c]; }
    double mu = s / (double)NNODES;
    double var = q / (double)NNODES - mu * mu;
    if (var < 0.0) var = 0.0;
    double inv = 1.0 / sqrt(var + (double)BN_EPS);
    float sc = (float)((double)g[c] * inv);
    scale[c] = sc;
    shift[c] = be[c] - (float)mu * sc;
}

// ---------------- tiled fp32 GEMM: C[N,NC] = f(A)[N,256] @ B[256,NC] + bias (+x) ----
// ATRANS: a -> relu(a*scale[k]+shift[k]) on load (BN+ReLU of previous layer)
// XEPI:   C += nf@Wemb + bemb (recomputed residual x)
// PART:   emit per-(rowblock,channel) partial sums/sumsq of C (BN stats)
template <int NC, bool ATRANS, bool XEPI, bool PART>
__global__ __launch_bounds__(256) void k_gemm(
    const float* __restrict__ A, const float* __restrict__ B, const float* __restrict__ bias,
    const float* __restrict__ scale, const float* __restrict__ shift,
    const float* __restrict__ nf, const float* __restrict__ Wemb, const float* __restrict__ bemb,
    float* __restrict__ C, float* __restrict__ psum, float* __restrict__ psq) {
    __shared__ float As[16][68];
    __shared__ float Bs[16][68];
    __shared__ float sSc[HID];
    __shared__ float sSh[HID];
    __shared__ float sNf[64][6];
    __shared__ float sXW[6][64];
    __shared__ float red[16][64];

    int tid = threadIdx.x;
    int rb = blockIdx.x, cb = blockIdx.y;
    int row0 = rb * 64, c0 = cb * 64;

    if (ATRANS) { sSc[tid] = scale[tid]; sSh[tid] = shift[tid]; }
    if (XEPI) {
        // FIX R1: 384 entries, 256 threads -> strided loop (was if(tid<384): rows 4,5 garbage)
        for (int t = tid; t < 384; t += 256) {
            int i = t / 64, cl = t % 64;
            sXW[i][cl] = Wemb[i * HID + c0 + cl];
        }
        if (tid < 64) {
            int n = row0 + tid;
#pragma unroll
            for (int i = 0; i < 6; ++i) sNf[tid][i] = (n < NNODES) ? nf[(size_t)n * 6 + i] : 0.f;
        }
    }
    int ty = tid / 16, tx = tid % 16;
    int a_n = tid >> 2, a_k = (tid & 3) * 4;
    int b_k = tid >> 4, b_c = (tid & 15) * 4;

    float acc[4][4] = {};
    __syncthreads();

    for (int k0 = 0; k0 < HID; k0 += 16) {
        // A tile 64x16
        {
            int n = row0 + a_n;
            float4 v = {0.f, 0.f, 0.f, 0.f};
            if (n < NNODES) v = *(const float4*)(A + (size_t)n * HID + k0 + a_k);
            float av[4] = {v.x, v.y, v.z, v.w};
#pragma unroll
            for (int j = 0; j < 4; ++j) {
                float x = av[j];
                if (ATRANS) {
                    int k = k0 + a_k + j;
                    x = fmaxf(fmaf(x, sSc[k], sSh[k]), 0.f);
                }
                As[a_k + j][a_n] = x;
            }
        }
        // B tile 16x64
        {
            float4 v = *(const float4*)(B + (size_t)(k0 + b_k) * NC + c0 + b_c);
            *(float4*)&Bs[b_k][b_c] = v;
        }
        __syncthreads();
#pragma unroll
        for (int kk = 0; kk < 16; ++kk) {
            float4 af = *(const float4*)&As[kk][ty * 4];
            float4 bf = *(const float4*)&Bs[kk][tx * 4];
            float a[4] = {af.x, af.y, af.z, af.w};
            float b[4] = {bf.x, bf.y, bf.z, bf.w};
#pragma unroll
            for (int i = 0; i < 4; ++i)
#pragma unroll
                for (int j = 0; j < 4; ++j) acc[i][j] = fmaf(a[i], b[j], acc[i][j]);
        }
        __syncthreads();
    }

    // epilogue
    float bv[4];
#pragma unroll
    for (int j = 0; j < 4; ++j) {
        bv[j] = bias[c0 + tx * 4 + j];
        if (XEPI) bv[j] += bemb[c0 + tx * 4 + j];
    }
    float ov[4][4];
#pragma unroll
    for (int i = 0; i < 4; ++i) {
        int n = row0 + ty * 4 + i;
#pragma unroll
        for (int j = 0; j < 4; ++j) {
            float v = acc[i][j] + bv[j];
            if (XEPI) {
#pragma unroll
                for (int l = 0; l < 6; ++l) v = fmaf(sNf[ty * 4 + i][l], sXW[l][tx * 4 + j], v);
            }
            ov[i][j] = v;
        }
        if (n < NNODES) {
            float4 o = {ov[i][0], ov[i][1], ov[i][2], ov[i][3]};
            *(float4*)(C + (size_t)n * NC + c0 + tx * 4) = o;
        }
    }
    if (PART) {
#pragma unroll
        for (int j = 0; j < 4; ++j) {
            float s = 0.f;
#pragma unroll
            for (int i = 0; i < 4; ++i) {
                int n = row0 + ty * 4 + i;
                if (n < NNODES) s += ov[i][j];
            }
            red[ty][tx * 4 + j] = s;
        }
        __syncthreads();
        if (tid < 64) {
            float s = 0.f;
#pragma unroll
            for (int r = 0; r < 16; ++r) s += red[r][tid];
            psum[rb * HID + c0 + tid] = s;
        }
        __syncthreads();
#pragma unroll
        for (int j = 0; j < 4; ++j) {
            float q = 0.f;
#pragma unroll
            for (int i = 0; i < 4; ++i) {
                int n = row0 + ty * 4 + i;
                if (n < NNODES) q = fmaf(ov[i][j], ov[i][j], q);
            }
            red[ty][tx * 4 + j] = q;
        }
        __syncthreads();
        if (tid < 64) {
            float q = 0.f;
#pragma unroll
            for (int r = 0; r < 16; ++r) q += red[r][tid];
            psq[rb * HID + c0 + tid] = q;
        }
    }
}

// ---------------- full 256-dim conv aggregation (layer 2): 1 wave per node ----------
__global__ __launch_bounds__(256) void k_agg(const int* __restrict__ row_ptr,
                                             const int* __restrict__ csr_src,
                                             const float* __restrict__ csr_w,
                                             const float* __restrict__ X,
                                             const float* __restrict__ dis,
                                             float* __restrict__ out) {
    int wid = threadIdx.x >> 6, lane = threadIdx.x & 63;
    int n = blockIdx.x * 4 + wid;
    if (n >= NNODES) return;
    int s = row_ptr[n], e = row_ptr[n + 1];
    float4 acc = {0.f, 0.f, 0.f, 0.f};
    for (int idx = s; idx < e; ++idx) {
        int sn = csr_src[idx];
        float w = csr_w[idx];
        float4 v = *(const float4*)(X + (size_t)sn * HID + lane * 4);
        acc.x = fmaf(w, v.x, acc.x);
        acc.y = fmaf(w, v.y, acc.y);
        acc.z = fmaf(w, v.z, acc.z);
        acc.w = fmaf(w, v.w, acc.w);
    }
    float r = dis[n];
    acc.x *= r; acc.y *= r; acc.z *= r; acc.w *= r;
    *(float4*)(out + (size_t)n * HID + lane * 4) = acc;
}

// ---------------- graph mean (sorted graph_ids, binary search) + classifier --------
__global__ __launch_bounds__(128) void k_mean_label(const float* __restrict__ Hout,
                                                    const int* __restrict__ gids,
                                                    const float* __restrict__ Wcls,
                                                    const float* __restrict__ bcls,
                                                    float* __restrict__ lab) {
    int g = blockIdx.x;
    int c = threadIdx.x;
    int lo = 0, hi = NNODES;
    while (lo < hi) { int mid = (lo + hi) >> 1; if (gids[mid] < g) lo = mid + 1; else hi = mid; }
    int s = lo;
    hi = NNODES;
    while (lo < hi) { int mid = (lo + hi) >> 1; if (gids[mid] < g + 1) lo = mid + 1; else hi = mid; }
    int e = lo;
    float acc = 0.f;
    for (int n = s; n < e; ++n) acc += Hout[(size_t)n * OUTD + c];
    int cnt = e - s;
    float y = acc / (float)max(cnt, 1);
    __shared__ float ys[OUTD];
    ys[c] = y;
    __syncthreads();
    if (c < NCLS) {
        float a = bcls[c];
        for (int k = 0; k < OUTD; ++k) a = fmaf(ys[k], Wcls[k * NCLS + c], a);
        lab[(size_t)g * NCLS + c] = a;
    }
}

// ---------------- host ----------------
extern "C" void kernel_launch(void* const* d_in, const int* in_sizes, int n_in,
                              void* d_out, int out_size, void* d_ws, size_t ws_size,
                              hipStream_t stream) {
    const float* nf   = (const float*)d_in[0];
    const int*   src  = (const int*)d_in[1];
    const int*   dst  = (const int*)d_in[2];
    const int*   gids = (const int*)d_in[3];
    const float* Wemb = (const float*)d_in[4];
    const float* bemb = (const float*)d_in[5];
    const float* Wc1  = (const float*)d_in[6];
    const float* bc1  = (const float*)d_in[7];
    const float* g1   = (const float*)d_in[8];
    const float* be1  = (const float*)d_in[9];
    const float* W2   = (const float*)d_in[10];
    const float* b2   = (const float*)d_in[11];
    const float* Wc2  = (const float*)d_in[12];
    const float* bc2  = (const float*)d_in[13];
    const float* g2   = (const float*)d_in[14];
    const float* be2  = (const float*)d_in[15];
    const float* W3   = (const float*)d_in[16];
    const float* b3   = (const float*)d_in[17];
    const float* Wcls = (const float*)d_in[18];
    const float* bcls = (const float*)d_in[19];

    float* out_h   = (float*)d_out;                 // [N, 128]
    float* out_lab = out_h + (size_t)NNODES * OUTD; // [G, 60]

    // workspace bump allocator (64-float = 256B granularity)
    float* ws = (float*)d_ws;
    size_t off = 0;
    auto take = [&](size_t n) { float* p = ws + off; off += (n + 63) & ~(size_t)63; return p; };
    float* B1      = take((size_t)NNODES * HID);   // h_pre1 -> A2
    float* B2      = take((size_t)NNODES * HID);   // h2 -> h_pre2
    int*   deg_out = (int*)take(NNODES);
    int*   deg_in  = (int*)take(NNODES);
    float* dout_is = take(NNODES);
    float* din_is  = take(NNODES);
    int*   row_ptr = (int*)take(NNODES + 1);
    int*   cursor  = (int*)take(NNODES);
    int*   csr_src = (int*)take(NEDGES);
    float* csr_w   = take(NEDGES);
    float* t6      = take((size_t)NNODES * 6);
    float* u1      = take(NNODES);
    float* M1      = take(6 * HID);
    float* v1      = take(HID);
    float* psum    = take((size_t)NROWBLK * HID);
    float* psq     = take((size_t)NROWBLK * HID);
    float* scale1  = take(HID);
    float* shift1  = take(HID);
    float* scale2  = take(HID);
    float* shift2  = take(HID);
    int*   bsum    = (int*)take(128);
    double* bn_tmp = (double*)take(2 * 2 * REDBLK * HID);  // doubles = 2 floats each

    // 1. zero degree arrays (ws is poisoned each call)
    k_zero_int<<<(2 * 100032 + 255) / 256, 256, 0, stream>>>(deg_out, 2 * 100032);
    // 2. degrees
    k_deg<<<(NEDGES + 255) / 256, 256, 0, stream>>>(src, dst, deg_out, deg_in);
    // 3. isqrt
    k_isqrt<<<(NNODES + 255) / 256, 256, 0, stream>>>(deg_out, deg_in, dout_is, din_is);
    // 4. CSR: hierarchical scan + scatter
    k_blk_sum<<<NSCANBLK, 256, 0, stream>>>(deg_in, bsum);
    k_scan_bsum<<<1, 64, 0, stream>>>(bsum);
    k_scan_local<<<NSCANBLK, 1024, 0, stream>>>(deg_in, bsum, row_ptr, cursor);
    k_scatter<<<(NEDGES + 255) / 256, 256, 0, stream>>>(src, dst, dout_is, cursor, csr_src, csr_w);
    // 5. M1 / v1
    k_small_mm<<<7, 256, 0, stream>>>(Wemb, bemb, Wc1, M1, v1);
    // 6. 6-dim aggregation
    k_agg6<<<(NNODES + 255) / 256, 256, 0, stream>>>(row_ptr, csr_src, csr_w, nf, t6, u1);
    // 7. fused layer 1 -> B1 (h_pre1) + BN1 partials
    k_layer1<<<NROWBLK, 256, 0, stream>>>(nf, Wemb, bemb, M1, v1, bc1, t6, u1, din_is, B1, psum, psq);
    // 8. BN1 scale/shift
    k_bn_part<<<REDBLK, 256, 0, stream>>>(psum, psq, bn_tmp);
    k_bn_final<<<1, 256, 0, stream>>>(bn_tmp, g1, be1, scale1, shift1);
    // 9. h2 = relu(bn1(h_pre1)) @ W2 + b2  -> B2
    k_gemm<HID, true, false, false><<<dim3(NROWBLK, 4), 256, 0, stream>>>(
        B1, W2, b2, scale1, shift1, nullptr, nullptr, nullptr, B2, nullptr, nullptr);
    // 10. A2 = conv-aggregate(h2) -> B1
    k_agg<<<NNODES / 4, 256, 0, stream>>>(row_ptr, csr_src, csr_w, B2, din_is, B1);
    // 11. h_pre2 = x + A2 @ Wc2 + bc2 -> B2, + BN2 partials (x recomputed in epilogue)
    k_gemm<HID, false, true, true><<<dim3(NROWBLK, 4), 256, 0, stream>>>(
        B1, Wc2, bc2, nullptr, nullptr, nf, Wemb, bemb, B2, psum, psq);
    // 12. BN2 scale/shift
    k_bn_part<<<REDBLK, 256, 0, stream>>>(psum, psq, bn_tmp);
    k_bn_final<<<1, 256, 0, stream>>>(bn_tmp, g2, be2, scale2, shift2);
    // 13. h_out = relu(bn2(h_pre2)) @ W3 + b3 -> d_out[0 : N*128]
    k_gemm<OUTD, true, false, false><<<dim3(NROWBLK, 2), 256, 0, stream>>>(
        B2, W3, b3, scale2, shift2, nullptr, nullptr, nullptr, out_h, nullptr, nullptr);
    // 14. graph mean + classifier -> d_out[N*128 : ]
    k_mean_label<<<NGRAPHS, OUTD, 0, stream>>>(out_h, gids, Wcls, bcls, out_lab);
}

// Round 3
// 925.825 us; speedup vs baseline: 1.2451x; 1.2451x over previous
//
#include <hip/hip_runtime.h>

#define NNODES 100000
#define MPAD   100032          // 1563 * 64
#define NEDGES 1600000
#define NGRAPHS 2000
#define HID 256
#define OUTD 128
#define NCLS 60
#define BN_EPS 1e-5f
#define NROWBLK 1563   // ceil(NNODES/64)
#define NSCANBLK 98    // ceil(NNODES/1024)
#define REDBLK 32

typedef __attribute__((ext_vector_type(8))) short bf16x8;
typedef __attribute__((ext_vector_type(4))) float f32x4;

__device__ __forceinline__ float b2f(unsigned short b) {
    unsigned int u = ((unsigned int)b) << 16;
    return __builtin_bit_cast(float, u);
}
__device__ __forceinline__ unsigned short f2b(float f) {
    unsigned int u = __builtin_bit_cast(unsigned int, f);
    u = (u + 0x7FFFu + ((u >> 16) & 1u)) >> 16;     // RNE
    return (unsigned short)u;
}

// ---------------- utility ----------------
__global__ void k_zero_int(int* __restrict__ p, int n) {
    int i = blockIdx.x * blockDim.x + threadIdx.x;
    if (i < n) p[i] = 0;
}

// ---------------- degrees ----------------
__global__ void k_deg(const int* __restrict__ src, const int* __restrict__ dst,
                      int* __restrict__ dout, int* __restrict__ din) {
    int e = blockIdx.x * blockDim.x + threadIdx.x;
    if (e < NEDGES) {
        atomicAdd(&dout[src[e]], 1);
        atomicAdd(&din[dst[e]], 1);
    }
}

__global__ void k_isqrt(const int* __restrict__ dout, const int* __restrict__ din,
                        float* __restrict__ dos, float* __restrict__ dis) {
    int i = blockIdx.x * blockDim.x + threadIdx.x;
    if (i < NNODES) {
        int a = dout[i], b = din[i];
        dos[i] = a > 0 ? 1.0f / sqrtf((float)a) : 0.0f;
        dis[i] = b > 0 ? 1.0f / sqrtf((float)b) : 0.0f;
    }
}

// ---------------- hierarchical exclusive scan of din -> row_ptr / cursor ----------
__global__ void k_blk_sum(const int* __restrict__ deg, int* __restrict__ bsum) {
    __shared__ int red[256];
    int blk = blockIdx.x, tid = threadIdx.x;
    int base = blk * 1024;
    int s = 0;
#pragma unroll
    for (int j = 0; j < 4; ++j) {
        int i = base + tid + j * 256;
        if (i < NNODES) s += deg[i];
    }
    red[tid] = s;
    __syncthreads();
    for (int off = 128; off > 0; off >>= 1) {
        if (tid < off) red[tid] += red[tid + off];
        __syncthreads();
    }
    if (tid == 0) bsum[blk] = red[0];
}

__global__ void k_scan_bsum(int* __restrict__ bsum) {
    if (threadIdx.x == 0) {
        int acc = 0;
        for (int i = 0; i < NSCANBLK; ++i) { int v = bsum[i]; bsum[i] = acc; acc += v; }
    }
}

__global__ void k_scan_local(const int* __restrict__ deg, const int* __restrict__ bsum,
                             int* __restrict__ row_ptr, int* __restrict__ cursor) {
    __shared__ int buf[1024];
    int blk = blockIdx.x, tid = threadIdx.x;
    int i = blk * 1024 + tid;
    int v = (i < NNODES) ? deg[i] : 0;
    buf[tid] = v;
    __syncthreads();
    for (int off = 1; off < 1024; off <<= 1) {
        int t = (tid >= off) ? buf[tid - off] : 0;
        __syncthreads();
        buf[tid] += t;
        __syncthreads();
    }
    int inc = buf[tid] + bsum[blk];
    if (i < NNODES) { row_ptr[i + 1] = inc; cursor[i] = inc - v; }
    if (i == 0) row_ptr[0] = 0;
}

__global__ void k_scatter(const int* __restrict__ src, const int* __restrict__ dst,
                          const float* __restrict__ dos, int* __restrict__ cursor,
                          int* __restrict__ csr_src, float* __restrict__ csr_w) {
    int e = blockIdx.x * blockDim.x + threadIdx.x;
    if (e < NEDGES) {
        int s = src[e], d = dst[e];
        int pos = atomicAdd(&cursor[d], 1);
        csr_src[pos] = s;
        csr_w[pos] = dos[s];
    }
}

// ---------------- weight convert: W[K][N] f32 -> Wt[N][K] bf16 ----------------
__global__ void k_wconv(const float* __restrict__ W, unsigned short* __restrict__ Wt,
                        int K, int N) {
    int idx = blockIdx.x * 256 + threadIdx.x;
    if (idx >= N * K) return;
    int n = idx / K, k = idx - n * K;
    Wt[idx] = f2b(W[(size_t)k * N + n]);
}

// ---------------- M1 = W_emb @ Wc1 (6x256), v1 = b_emb @ Wc1 (256) ----------------
__global__ void k_small_mm(const float* __restrict__ Wemb, const float* __restrict__ bemb,
                           const float* __restrict__ Wc1, float* __restrict__ M1,
                           float* __restrict__ v1) {
    int c = threadIdx.x;
    int bi = blockIdx.x;
    float acc = 0.f;
    if (bi < 6) {
        for (int k = 0; k < HID; ++k) acc = fmaf(Wemb[bi * HID + k], Wc1[k * HID + c], acc);
        M1[bi * HID + c] = acc;
    } else {
        for (int k = 0; k < HID; ++k) acc = fmaf(bemb[k], Wc1[k * HID + c], acc);
        v1[c] = acc;
    }
}

// ---------------- 6-dim edge aggregation (for collapsed layer-1 conv) ----------------
__global__ void k_agg6(const int* __restrict__ row_ptr, const int* __restrict__ csr_src,
                       const float* __restrict__ csr_w, const float* __restrict__ nf,
                       float* __restrict__ t6, float* __restrict__ u1) {
    int n = blockIdx.x * blockDim.x + threadIdx.x;
    if (n >= NNODES) return;
    float a0 = 0, a1 = 0, a2 = 0, a3 = 0, a4 = 0, a5 = 0, au = 0;
    int s = row_ptr[n], e = row_ptr[n + 1];
    for (int idx = s; idx < e; ++idx) {
        int sn = csr_src[idx];
        float w = csr_w[idx];
        const float* p = nf + (size_t)sn * 6;
        a0 = fmaf(w, p[0], a0); a1 = fmaf(w, p[1], a1); a2 = fmaf(w, p[2], a2);
        a3 = fmaf(w, p[3], a3); a4 = fmaf(w, p[4], a4); a5 = fmaf(w, p[5], a5);
        au += w;
    }
    float* t = t6 + (size_t)n * 6;
    t[0] = a0; t[1] = a1; t[2] = a2; t[3] = a3; t[4] = a4; t[5] = a5;
    u1[n] = au;
}

// ---------------- fused layer 1 -> bf16 h_pre1 + fp32 BN partials ----------------
__global__ __launch_bounds__(256) void k_layer1(
    const float* __restrict__ nf, const float* __restrict__ Wemb, const float* __restrict__ bemb,
    const float* __restrict__ M1, const float* __restrict__ v1, const float* __restrict__ bc1,
    const float* __restrict__ t6, const float* __restrict__ u1, const float* __restrict__ dis,
    unsigned short* __restrict__ H, float* __restrict__ psum, float* __restrict__ psq) {
    __shared__ float s_nf[64][6];
    __shared__ float s_t6[64][6];
    __shared__ float s_u[64];
    __shared__ float s_r[64];
    int blk = blockIdx.x;
    int n0 = blk * 64;
    int tid = threadIdx.x;
    for (int t = tid; t < 384; t += 256) {
        int nl = t / 6, i = t % 6;
        int n = n0 + nl;
        s_nf[nl][i] = (n < NNODES) ? nf[(size_t)n * 6 + i] : 0.f;
        s_t6[nl][i] = (n < NNODES) ? t6[(size_t)n * 6 + i] : 0.f;
    }
    if (tid < 64) {
        int n = n0 + tid;
        s_u[tid] = (n < NNODES) ? u1[n] : 0.f;
        s_r[tid] = (n < NNODES) ? dis[n] : 0.f;
    }
    int c = tid;
    float wc[6], mc[6];
#pragma unroll
    for (int i = 0; i < 6; ++i) { wc[i] = Wemb[i * HID + c]; mc[i] = M1[i * HID + c]; }
    float v1c = v1[c];
    float bsum = bemb[c] + bc1[c];
    __syncthreads();
    float ps = 0.f, pq = 0.f;
    int nmax = min(64, NNODES - n0);
    for (int nl = 0; nl < nmax; ++nl) {
        float nfd = 0.f, td = 0.f;
#pragma unroll
        for (int i = 0; i < 6; ++i) {
            nfd = fmaf(s_nf[nl][i], wc[i], nfd);
            td = fmaf(s_t6[nl][i], mc[i], td);
        }
        float val = nfd + s_r[nl] * (td + s_u[nl] * v1c) + bsum;
        H[(size_t)(n0 + nl) * HID + c] = f2b(val);
        ps += val;
        pq = fmaf(val, val, pq);
    }
    for (int nl = nmax; nl < 64; ++nl) H[(size_t)(n0 + nl) * HID + c] = 0;  // zero pad rows
    psum[blk * HID + c] = ps;
    psq[blk * HID + c] = pq;
}

// ---------------- BN two-stage reduce -> scale/shift ----------------
__global__ void k_bn_part(const float* __restrict__ psum, const float* __restrict__ psq,
                          double* __restrict__ tmp) {
    int c = threadIdx.x;
    int s = blockIdx.x;
    double a = 0.0, b = 0.0;
    for (int bb = s; bb < NROWBLK; bb += REDBLK) {
        a += psum[bb * HID + c];
        b += psq[bb * HID + c];
    }
    tmp[s * HID + c] = a;
    tmp[(REDBLK + s) * HID + c] = b;
}

__global__ void k_bn_final(const double* __restrict__ tmp, const float* __restrict__ g,
                           const float* __restrict__ be, float* __restrict__ scale,
                           float* __restrict__ shift) {
    int c = threadIdx.x;
    double s = 0.0, q = 0.0;
    for (int i = 0; i < REDBLK; ++i) { s += tmp[i * HID + c]; q += tmp[(REDBLK + i) * HID + c]; }
    double mu = s / (double)NNODES;
    double var = q / (double)NNODES - mu * mu;
    if (var < 0.0) var = 0.0;
    double inv = 1.0 / sqrt(var + (double)BN_EPS);
    float sc = (float)((double)g[c] * inv);
    scale[c] = sc;
    shift[c] = be[c] - (float)mu * sc;
}

// ================= bf16 MFMA GEMM =================
// C[M,NC] = f(A)[M,256] @ B[256,NC] + bias (+x residual)
// A: [MPAD][256] bf16.  Bt: [NC][256] bf16 (B transposed).
// ATRANS: a -> relu(a*scale[k]+shift[k]) at staging (fused BN+ReLU)
// XEPI:   += nf@Wemb + bemb (recomputed residual x, fp32)
// PART:   per-(rowblock, col) partial sum/sumsq of outputs (BN stats)
// OUTF32: write fp32 (else bf16)
// Tile 64x64, K=256 fully LDS-resident, XOR-swizzled 16B chunks.
template <int NC, bool ATRANS, bool XEPI, bool PART, bool OUTF32>
__global__ __launch_bounds__(256, 2) void k_mgemm(
    const unsigned short* __restrict__ A, const unsigned short* __restrict__ Bt,
    const float* __restrict__ bias,
    const float* __restrict__ scale, const float* __restrict__ shift,
    const float* __restrict__ nf, const float* __restrict__ Wemb, const float* __restrict__ bemb,
    unsigned short* __restrict__ Cb, float* __restrict__ Cf,
    float* __restrict__ psum, float* __restrict__ psq) {
    __shared__ unsigned short As[64 * 256];
    __shared__ unsigned short Bs[64 * 256];
    __shared__ float sSc[HID];
    __shared__ float sSh[HID];
    __shared__ float sNf[64][6];
    __shared__ float sXW[6][64];
    __shared__ float redS[2][64];
    __shared__ float redQ[2][64];

    int tid = threadIdx.x;
    int rb = blockIdx.x, cb = blockIdx.y;
    int row0 = rb * 64, c0 = cb * 64;

    if (ATRANS) { sSc[tid] = scale[tid]; sSh[tid] = shift[tid]; }
    if (XEPI) {
        for (int t = tid; t < 384; t += 256) {
            int i = t / 64, cl = t % 64;
            sXW[i][cl] = Wemb[i * HID + c0 + cl];
        }
        if (tid < 64) {
            int n = row0 + tid;
#pragma unroll
            for (int i = 0; i < 6; ++i) sNf[tid][i] = (n < NNODES) ? nf[(size_t)n * 6 + i] : 0.f;
        }
    }
    if (ATRANS) __syncthreads();   // sSc/sSh consumed during staging

    // ---- stage A tile 64x256 bf16 (2048 x 16B chunks, 8 per thread) ----
#pragma unroll
    for (int i = 0; i < 8; ++i) {
        int g = i * 256 + tid;
        int row = g >> 5, kc = g & 31;
        uint4 v = *(const uint4*)(A + (size_t)(row0 + row) * 256 + kc * 8);
        if (ATRANS) {
            unsigned int w[4] = {v.x, v.y, v.z, v.w};
#pragma unroll
            for (int q = 0; q < 4; ++q) {
                int k0 = kc * 8 + q * 2;
                float f0 = b2f((unsigned short)(w[q] & 0xffffu));
                float f1 = b2f((unsigned short)(w[q] >> 16));
                f0 = fmaxf(fmaf(f0, sSc[k0], sSh[k0]), 0.f);
                f1 = fmaxf(fmaf(f1, sSc[k0 + 1], sSh[k0 + 1]), 0.f);
                w[q] = (unsigned int)f2b(f0) | ((unsigned int)f2b(f1) << 16);
            }
            v.x = w[0]; v.y = w[1]; v.z = w[2]; v.w = w[3];
        }
        int pkc = kc ^ (row & 7);
        *(uint4*)(&As[row * 256 + pkc * 8]) = v;
    }
    // ---- stage B^T tile 64x256 bf16 ----
#pragma unroll
    for (int i = 0; i < 8; ++i) {
        int g = i * 256 + tid;
        int row = g >> 5, kc = g & 31;
        uint4 v = *(const uint4*)(Bt + (size_t)(c0 + row) * 256 + kc * 8);
        int pkc = kc ^ (row & 7);
        *(uint4*)(&Bs[row * 256 + pkc * 8]) = v;
    }
    __syncthreads();

    int w = tid >> 6, lane = tid & 63;
    int wm = w >> 1, wn = w & 1;            // 2x2 wave grid, each wave 32x32
    int lrow = lane & 15, lk = lane >> 4;

    f32x4 acc[2][2] = {};
#pragma unroll
    for (int ks = 0; ks < 8; ++ks) {        // K = 8 x 32
        bf16x8 af[2], bfr[2];
#pragma unroll
        for (int fm = 0; fm < 2; ++fm) {
            int r = wm * 32 + fm * 16 + lrow;
            int kc = ks * 4 + lk;
            af[fm] = *(const bf16x8*)(&As[r * 256 + (kc ^ (r & 7)) * 8]);
        }
#pragma unroll
        for (int fn = 0; fn < 2; ++fn) {
            int r = wn * 32 + fn * 16 + lrow;
            int kc = ks * 4 + lk;
            bfr[fn] = *(const bf16x8*)(&Bs[r * 256 + (kc ^ (r & 7)) * 8]);
        }
#pragma unroll
        for (int fm = 0; fm < 2; ++fm)
#pragma unroll
            for (int fn = 0; fn < 2; ++fn)
                acc[fm][fn] = __builtin_amdgcn_mfma_f32_16x16x32_bf16(af[fm], bfr[fn], acc[fm][fn], 0, 0, 0);
    }

    // ---- epilogue: C/D layout col=lane&15, row=(lane>>4)*4+reg ----
    float pS[2] = {0.f, 0.f}, pQ[2] = {0.f, 0.f};
#pragma unroll
    for (int fn = 0; fn < 2; ++fn) {
        int cl = wn * 32 + fn * 16 + lrow;
        int gc = c0 + cl;
        float bv = bias[gc];
        if (XEPI) bv += bemb[gc];
#pragma unroll
        for (int fm = 0; fm < 2; ++fm) {
#pragma unroll
            for (int r = 0; r < 4; ++r) {
                int rl = wm * 32 + fm * 16 + lk * 4 + r;
                int gr = row0 + rl;
                float val = acc[fm][fn][r] + bv;
                if (XEPI) {
#pragma unroll
                    for (int l = 0; l < 6; ++l) val = fmaf(sNf[rl][l], sXW[l][cl], val);
                }
                bool ok = gr < NNODES;
                if (ok) {
                    if (OUTF32) Cf[(size_t)gr * NC + gc] = val;
                    else        Cb[(size_t)gr * NC + gc] = f2b(val);
                    if (PART) { pS[fn] += val; pQ[fn] = fmaf(val, val, pQ[fn]); }
                }
            }
        }
    }
    if (PART) {
#pragma unroll
        for (int fn = 0; fn < 2; ++fn) {
            float s = pS[fn], q = pQ[fn];
            s += __shfl_xor(s, 16); s += __shfl_xor(s, 32);
            q += __shfl_xor(q, 16); q += __shfl_xor(q, 32);
            if (lk == 0) {
                int cl = wn * 32 + fn * 16 + lrow;
                redS[wm][cl] = s;
                redQ[wm][cl] = q;
            }
        }
        __syncthreads();
        if (tid < 64) {
            psum[(size_t)rb * HID + c0 + tid] = redS[0][tid] + redS[1][tid];
            psq [(size_t)rb * HID + c0 + tid] = redQ[0][tid] + redQ[1][tid];
        }
    }
}

// ---------------- bf16 conv aggregation (layer 2): 1 wave per node ----------
__global__ __launch_bounds__(256) void k_agg(const int* __restrict__ row_ptr,
                                             const int* __restrict__ csr_src,
                                             const float* __restrict__ csr_w,
                                             const unsigned short* __restrict__ X,
                                             const float* __restrict__ dis,
                                             unsigned short* __restrict__ out) {
    int wid = threadIdx.x >> 6, lane = threadIdx.x & 63;
    int n = blockIdx.x * 4 + wid;
    if (n >= NNODES) return;
    int s = row_ptr[n], e = row_ptr[n + 1];
    float a0 = 0.f, a1 = 0.f, a2 = 0.f, a3 = 0.f;
    for (int idx = s; idx < e; ++idx) {
        int sn = csr_src[idx];
        float w = csr_w[idx];
        uint2 v = ((const uint2*)(X + (size_t)sn * HID))[lane];   // 4 bf16
        a0 = fmaf(w, b2f((unsigned short)(v.x & 0xffffu)), a0);
        a1 = fmaf(w, b2f((unsigned short)(v.x >> 16)), a1);
        a2 = fmaf(w, b2f((unsigned short)(v.y & 0xffffu)), a2);
        a3 = fmaf(w, b2f((unsigned short)(v.y >> 16)), a3);
    }
    float r = dis[n];
    ushort4 o;
    o.x = f2b(a0 * r); o.y = f2b(a1 * r); o.z = f2b(a2 * r); o.w = f2b(a3 * r);
    ((ushort4*)(out + (size_t)n * HID))[lane] = o;
}

// ---------------- graph mean (sorted graph_ids, binary search) + classifier --------
__global__ __launch_bounds__(128) void k_mean_label(const float* __restrict__ Hout,
                                                    const int* __restrict__ gids,
                                                    const float* __restrict__ Wcls,
                                                    const float* __restrict__ bcls,
                                                    float* __restrict__ lab) {
    int g = blockIdx.x;
    int c = threadIdx.x;
    int lo = 0, hi = NNODES;
    while (lo < hi) { int mid = (lo + hi) >> 1; if (gids[mid] < g) lo = mid + 1; else hi = mid; }
    int s = lo;
    hi = NNODES;
    while (lo < hi) { int mid = (lo + hi) >> 1; if (gids[mid] < g + 1) lo = mid + 1; else hi = mid; }
    int e = lo;
    float acc = 0.f;
    for (int n = s; n < e; ++n) acc += Hout[(size_t)n * OUTD + c];
    int cnt = e - s;
    float y = acc / (float)max(cnt, 1);
    __shared__ float ys[OUTD];
    ys[c] = y;
    __syncthreads();
    if (c < NCLS) {
        float a = bcls[c];
        for (int k = 0; k < OUTD; ++k) a = fmaf(ys[k], Wcls[k * NCLS + c], a);
        lab[(size_t)g * NCLS + c] = a;
    }
}

// ---------------- host ----------------
extern "C" void kernel_launch(void* const* d_in, const int* in_sizes, int n_in,
                              void* d_out, int out_size, void* d_ws, size_t ws_size,
                              hipStream_t stream) {
    const float* nf   = (const float*)d_in[0];
    const int*   src  = (const int*)d_in[1];
    const int*   dst  = (const int*)d_in[2];
    const int*   gids = (const int*)d_in[3];
    const float* Wemb = (const float*)d_in[4];
    const float* bemb = (const float*)d_in[5];
    const float* Wc1  = (const float*)d_in[6];
    const float* bc1  = (const float*)d_in[7];
    const float* g1   = (const float*)d_in[8];
    const float* be1  = (const float*)d_in[9];
    const float* W2   = (const float*)d_in[10];
    const float* b2   = (const float*)d_in[11];
    const float* Wc2  = (const float*)d_in[12];
    const float* bc2  = (const float*)d_in[13];
    const float* g2   = (const float*)d_in[14];
    const float* be2  = (const float*)d_in[15];
    const float* W3   = (const float*)d_in[16];
    const float* b3   = (const float*)d_in[17];
    const float* Wcls = (const float*)d_in[18];
    const float* bcls = (const float*)d_in[19];

    float* out_h   = (float*)d_out;                 // [N, 128] fp32
    float* out_lab = out_h + (size_t)NNODES * OUTD; // [G, 60]

    // workspace bump allocator (floats, 256B granularity)
    float* ws = (float*)d_ws;
    size_t off = 0;
    auto take = [&](size_t n) { float* p = ws + off; off += (n + 63) & ~(size_t)63; return p; };
    unsigned short* actA = (unsigned short*)take((size_t)MPAD * HID / 2);  // bf16 [MPAD][256]
    unsigned short* actB = (unsigned short*)take((size_t)MPAD * HID / 2);  // bf16 [MPAD][256]
    unsigned short* Wt2  = (unsigned short*)take(HID * HID / 2);
    unsigned short* Wtc2 = (unsigned short*)take(HID * HID / 2);
    unsigned short* Wt3  = (unsigned short*)take(OUTD * HID / 2);
    int*   deg_out = (int*)take(NNODES);
    int*   deg_in  = (int*)take(NNODES);
    float* dout_is = take(NNODES);
    float* din_is  = take(NNODES);
    int*   row_ptr = (int*)take(NNODES + 1);
    int*   cursor  = (int*)take(NNODES);
    int*   csr_src = (int*)take(NEDGES);
    float* csr_w   = take(NEDGES);
    float* t6      = take((size_t)NNODES * 6);
    float* u1      = take(NNODES);
    float* M1      = take(6 * HID);
    float* v1      = take(HID);
    float* psum    = take((size_t)NROWBLK * HID);
    float* psq     = take((size_t)NROWBLK * HID);
    float* scale1  = take(HID);
    float* shift1  = take(HID);
    float* scale2  = take(HID);
    float* shift2  = take(HID);
    int*   bsum    = (int*)take(128);
    double* bn_tmp = (double*)take(2 * 2 * REDBLK * HID);

    // 1. zero degree arrays
    k_zero_int<<<(2 * 100032 + 255) / 256, 256, 0, stream>>>(deg_out, 2 * 100032);
    // 2. degrees
    k_deg<<<(NEDGES + 255) / 256, 256, 0, stream>>>(src, dst, deg_out, deg_in);
    // 3. isqrt
    k_isqrt<<<(NNODES + 255) / 256, 256, 0, stream>>>(deg_out, deg_in, dout_is, din_is);
    // 4. CSR: hierarchical scan + scatter
    k_blk_sum<<<NSCANBLK, 256, 0, stream>>>(deg_in, bsum);
    k_scan_bsum<<<1, 64, 0, stream>>>(bsum);
    k_scan_local<<<NSCANBLK, 1024, 0, stream>>>(deg_in, bsum, row_ptr, cursor);
    k_scatter<<<(NEDGES + 255) / 256, 256, 0, stream>>>(src, dst, dout_is, cursor, csr_src, csr_w);
    // 5. weight conversion + M1/v1
    k_wconv<<<(HID * HID + 255) / 256, 256, 0, stream>>>(W2, Wt2, HID, HID);
    k_wconv<<<(HID * HID + 255) / 256, 256, 0, stream>>>(Wc2, Wtc2, HID, HID);
    k_wconv<<<(HID * OUTD + 255) / 256, 256, 0, stream>>>(W3, Wt3, HID, OUTD);
    k_small_mm<<<7, 256, 0, stream>>>(Wemb, bemb, Wc1, M1, v1);
    // 6. 6-dim aggregation
    k_agg6<<<(NNODES + 255) / 256, 256, 0, stream>>>(row_ptr, csr_src, csr_w, nf, t6, u1);
    // 7. fused layer 1 -> actA (h_pre1 bf16) + BN1 partials
    k_layer1<<<NROWBLK, 256, 0, stream>>>(nf, Wemb, bemb, M1, v1, bc1, t6, u1, din_is,
                                          actA, psum, psq);
    // 8. BN1 scale/shift
    k_bn_part<<<REDBLK, 256, 0, stream>>>(psum, psq, bn_tmp);
    k_bn_final<<<1, 256, 0, stream>>>(bn_tmp, g1, be1, scale1, shift1);
    // 9. h2 = relu(bn1(h_pre1)) @ W2 + b2 -> actB (bf16)
    k_mgemm<HID, true, false, false, false><<<dim3(NROWBLK, 4), 256, 0, stream>>>(
        actA, Wt2, b2, scale1, shift1, nullptr, nullptr, nullptr, actB, nullptr, nullptr, nullptr);
    // 10. A2 = conv-aggregate(h2) -> actA (bf16)
    k_agg<<<NNODES / 4, 256, 0, stream>>>(row_ptr, csr_src, csr_w, actB, din_is, actA);
    // 11. h_pre2 = x + A2 @ Wc2 + bc2 -> actB (bf16) + BN2 partials
    k_mgemm<HID, false, true, true, false><<<dim3(NROWBLK, 4), 256, 0, stream>>>(
        actA, Wtc2, bc2, nullptr, nullptr, nf, Wemb, bemb, actB, nullptr, psum, psq);
    // 12. BN2 scale/shift
    k_bn_part<<<REDBLK, 256, 0, stream>>>(psum, psq, bn_tmp);
    k_bn_final<<<1, 256, 0, stream>>>(bn_tmp, g2, be2, scale2, shift2);
    // 13. h_out = relu(bn2(h_pre2)) @ W3 + b3 -> d_out fp32
    k_mgemm<OUTD, true, false, false, true><<<dim3(NROWBLK, 2), 256, 0, stream>>>(
        actB, Wt3, b3, scale2, shift2, nullptr, nullptr, nullptr, nullptr, out_h, nullptr, nullptr);
    // 14. graph mean + classifier
    k_mean_label<<<NGRAPHS, OUTD, 0, stream>>>(out_h, gids, Wcls, bcls, out_lab);
}

// Round 4
// 779.630 us; speedup vs baseline: 1.4786x; 1.1875x over previous
//
#include <hip/hip_runtime.h>

#define NNODES 100000
#define MPAD   100032          // 1563 * 64
#define NEDGES 1600000
#define NGRAPHS 2000
#define HID 256
#define OUTD 128
#define NCLS 60
#define BN_EPS 1e-5f
#define NROWBLK 1563   // ceil(NNODES/64)
#define NSCANBLK 98    // ceil(NNODES/1024)
#define REDBLK 32

typedef __attribute__((ext_vector_type(8))) short bf16x8;
typedef __attribute__((ext_vector_type(4))) float f32x4;

__device__ __forceinline__ float b2f(unsigned short b) {
    unsigned int u = ((unsigned int)b) << 16;
    return __builtin_bit_cast(float, u);
}
__device__ __forceinline__ unsigned short f2b(float f) {
    unsigned int u = __builtin_bit_cast(unsigned int, f);
    u = (u + 0x7FFFu + ((u >> 16) & 1u)) >> 16;     // RNE
    return (unsigned short)u;
}

// ---------------- utility ----------------
__global__ void k_zero_int(int* __restrict__ p, int n) {
    int i = blockIdx.x * blockDim.x + threadIdx.x;
    if (i < n) p[i] = 0;
}

// ---------------- degrees ----------------
__global__ void k_deg(const int* __restrict__ src, const int* __restrict__ dst,
                      int* __restrict__ dout, int* __restrict__ din) {
    int e = blockIdx.x * blockDim.x + threadIdx.x;
    if (e < NEDGES) {
        atomicAdd(&dout[src[e]], 1);
        atomicAdd(&din[dst[e]], 1);
    }
}

__global__ void k_isqrt(const int* __restrict__ dout, const int* __restrict__ din,
                        float* __restrict__ dos, float* __restrict__ dis) {
    int i = blockIdx.x * blockDim.x + threadIdx.x;
    if (i < NNODES) {
        int a = dout[i], b = din[i];
        dos[i] = a > 0 ? 1.0f / sqrtf((float)a) : 0.0f;
        dis[i] = b > 0 ? 1.0f / sqrtf((float)b) : 0.0f;
    }
}

// ---------------- hierarchical exclusive scan of din -> row_ptr / cursor ----------
__global__ void k_blk_sum(const int* __restrict__ deg, int* __restrict__ bsum) {
    __shared__ int red[256];
    int blk = blockIdx.x, tid = threadIdx.x;
    int base = blk * 1024;
    int s = 0;
#pragma unroll
    for (int j = 0; j < 4; ++j) {
        int i = base + tid + j * 256;
        if (i < NNODES) s += deg[i];
    }
    red[tid] = s;
    __syncthreads();
    for (int off = 128; off > 0; off >>= 1) {
        if (tid < off) red[tid] += red[tid + off];
        __syncthreads();
    }
    if (tid == 0) bsum[blk] = red[0];
}

__global__ void k_scan_bsum(int* __restrict__ bsum) {
    if (threadIdx.x == 0) {
        int acc = 0;
        for (int i = 0; i < NSCANBLK; ++i) { int v = bsum[i]; bsum[i] = acc; acc += v; }
    }
}

__global__ void k_scan_local(const int* __restrict__ deg, const int* __restrict__ bsum,
                             int* __restrict__ row_ptr, int* __restrict__ cursor) {
    __shared__ int buf[1024];
    int blk = blockIdx.x, tid = threadIdx.x;
    int i = blk * 1024 + tid;
    int v = (i < NNODES) ? deg[i] : 0;
    buf[tid] = v;
    __syncthreads();
    for (int off = 1; off < 1024; off <<= 1) {
        int t = (tid >= off) ? buf[tid - off] : 0;
        __syncthreads();
        buf[tid] += t;
        __syncthreads();
    }
    int inc = buf[tid] + bsum[blk];
    if (i < NNODES) { row_ptr[i + 1] = inc; cursor[i] = inc - v; }
    if (i == 0) row_ptr[0] = 0;
}

// packed edge record: {src_node, weight_bits}
__global__ void k_scatter(const int* __restrict__ src, const int* __restrict__ dst,
                          const float* __restrict__ dos, int* __restrict__ cursor,
                          int2* __restrict__ csr_ew) {
    int e = blockIdx.x * blockDim.x + threadIdx.x;
    if (e < NEDGES) {
        int s = src[e], d = dst[e];
        int pos = atomicAdd(&cursor[d], 1);
        csr_ew[pos] = make_int2(s, __float_as_int(dos[s]));
    }
}

// ---------------- weight convert: W[K][N] f32 -> Wt[N][K] bf16 ----------------
__global__ void k_wconv(const float* __restrict__ W, unsigned short* __restrict__ Wt,
                        int K, int N) {
    int idx = blockIdx.x * 256 + threadIdx.x;
    if (idx >= N * K) return;
    int n = idx / K, k = idx - n * K;
    Wt[idx] = f2b(W[(size_t)k * N + n]);
}

// ---------------- M1 = W_emb @ Wc1 (6x256), v1 = b_emb @ Wc1 (256) ----------------
__global__ void k_small_mm(const float* __restrict__ Wemb, const float* __restrict__ bemb,
                           const float* __restrict__ Wc1, float* __restrict__ M1,
                           float* __restrict__ v1) {
    int c = threadIdx.x;
    int bi = blockIdx.x;
    float acc = 0.f;
    if (bi < 6) {
        for (int k = 0; k < HID; ++k) acc = fmaf(Wemb[bi * HID + k], Wc1[k * HID + c], acc);
        M1[bi * HID + c] = acc;
    } else {
        for (int k = 0; k < HID; ++k) acc = fmaf(bemb[k], Wc1[k * HID + c], acc);
        v1[c] = acc;
    }
}

// ---------------- 6-dim edge aggregation (collapsed layer-1 conv) ----------------
__global__ void k_agg6(const int* __restrict__ row_ptr, const int2* __restrict__ csr_ew,
                       const float* __restrict__ nf,
                       float* __restrict__ t6, float* __restrict__ u1) {
    int n = blockIdx.x * blockDim.x + threadIdx.x;
    if (n >= NNODES) return;
    float a0 = 0, a1 = 0, a2 = 0, a3 = 0, a4 = 0, a5 = 0, au = 0;
    int s = row_ptr[n], e = row_ptr[n + 1];
    int i = s;
    for (; i + 2 <= e; i += 2) {
        int2 g0 = csr_ew[i], g1 = csr_ew[i + 1];
        float w0 = __int_as_float(g0.y), w1 = __int_as_float(g1.y);
        const float* p0 = nf + (size_t)g0.x * 6;
        const float* p1 = nf + (size_t)g1.x * 6;
        a0 = fmaf(w0, p0[0], a0); a1 = fmaf(w0, p0[1], a1); a2 = fmaf(w0, p0[2], a2);
        a3 = fmaf(w0, p0[3], a3); a4 = fmaf(w0, p0[4], a4); a5 = fmaf(w0, p0[5], a5);
        au += w0;
        a0 = fmaf(w1, p1[0], a0); a1 = fmaf(w1, p1[1], a1); a2 = fmaf(w1, p1[2], a2);
        a3 = fmaf(w1, p1[3], a3); a4 = fmaf(w1, p1[4], a4); a5 = fmaf(w1, p1[5], a5);
        au += w1;
    }
    for (; i < e; ++i) {
        int2 g0 = csr_ew[i];
        float w = __int_as_float(g0.y);
        const float* p = nf + (size_t)g0.x * 6;
        a0 = fmaf(w, p[0], a0); a1 = fmaf(w, p[1], a1); a2 = fmaf(w, p[2], a2);
        a3 = fmaf(w, p[3], a3); a4 = fmaf(w, p[4], a4); a5 = fmaf(w, p[5], a5);
        au += w;
    }
    float* t = t6 + (size_t)n * 6;
    t[0] = a0; t[1] = a1; t[2] = a2; t[3] = a3; t[4] = a4; t[5] = a5;
    u1[n] = au;
}

// ---------------- fused layer 1 -> bf16 h_pre1 + fp32 BN partials ----------------
__global__ __launch_bounds__(256) void k_layer1(
    const float* __restrict__ nf, const float* __restrict__ Wemb, const float* __restrict__ bemb,
    const float* __restrict__ M1, const float* __restrict__ v1, const float* __restrict__ bc1,
    const float* __restrict__ t6, const float* __restrict__ u1, const float* __restrict__ dis,
    unsigned short* __restrict__ H, float* __restrict__ psum, float* __restrict__ psq) {
    __shared__ float s_nf[64][6];
    __shared__ float s_t6[64][6];
    __shared__ float s_u[64];
    __shared__ float s_r[64];
    int blk = blockIdx.x;
    int n0 = blk * 64;
    int tid = threadIdx.x;
    for (int t = tid; t < 384; t += 256) {
        int nl = t / 6, i = t % 6;
        int n = n0 + nl;
        s_nf[nl][i] = (n < NNODES) ? nf[(size_t)n * 6 + i] : 0.f;
        s_t6[nl][i] = (n < NNODES) ? t6[(size_t)n * 6 + i] : 0.f;
    }
    if (tid < 64) {
        int n = n0 + tid;
        s_u[tid] = (n < NNODES) ? u1[n] : 0.f;
        s_r[tid] = (n < NNODES) ? dis[n] : 0.f;
    }
    int c = tid;
    float wc[6], mc[6];
#pragma unroll
    for (int i = 0; i < 6; ++i) { wc[i] = Wemb[i * HID + c]; mc[i] = M1[i * HID + c]; }
    float v1c = v1[c];
    float bsum = bemb[c] + bc1[c];
    __syncthreads();
    float ps = 0.f, pq = 0.f;
    int nmax = min(64, NNODES - n0);
    for (int nl = 0; nl < nmax; ++nl) {
        float nfd = 0.f, td = 0.f;
#pragma unroll
        for (int i = 0; i < 6; ++i) {
            nfd = fmaf(s_nf[nl][i], wc[i], nfd);
            td = fmaf(s_t6[nl][i], mc[i], td);
        }
        float val = nfd + s_r[nl] * (td + s_u[nl] * v1c) + bsum;
        H[(size_t)(n0 + nl) * HID + c] = f2b(val);
        ps += val;
        pq = fmaf(val, val, pq);
    }
    for (int nl = nmax; nl < 64; ++nl) H[(size_t)(n0 + nl) * HID + c] = 0;  // zero pad rows
    psum[blk * HID + c] = ps;
    psq[blk * HID + c] = pq;
}

// ---------------- BN two-stage reduce -> scale/shift ----------------
__global__ void k_bn_part(const float* __restrict__ psum, const float* __restrict__ psq,
                          double* __restrict__ tmp) {
    int c = threadIdx.x;
    int s = blockIdx.x;
    double a = 0.0, b = 0.0;
    for (int bb = s; bb < NROWBLK; bb += REDBLK) {
        a += psum[bb * HID + c];
        b += psq[bb * HID + c];
    }
    tmp[s * HID + c] = a;
    tmp[(REDBLK + s) * HID + c] = b;
}

__global__ void k_bn_final(const double* __restrict__ tmp, const float* __restrict__ g,
                           const float* __restrict__ be, float* __restrict__ scale,
                           float* __restrict__ shift) {
    int c = threadIdx.x;
    double s = 0.0, q = 0.0;
    for (int i = 0; i < REDBLK; ++i) { s += tmp[i * HID + c]; q += tmp[(REDBLK + i) * HID + c]; }
    double mu = s / (double)NNODES;
    double var = q / (double)NNODES - mu * mu;
    if (var < 0.0) var = 0.0;
    double inv = 1.0 / sqrt(var + (double)BN_EPS);
    float sc = (float)((double)g[c] * inv);
    scale[c] = sc;
    shift[c] = be[c] - (float)mu * sc;
}

// ================= bf16 MFMA GEMM, A-panel reused across all column blocks =========
// C[M,NC] = f(A)[M,256] @ B[256,NC] + bias (+x residual)
// Grid: 1-D over 64-row panels. Each block stages its A-tile (64x256 bf16) ONCE,
// then loops over NC/64 column blocks streaming B^T tiles through LDS.
// ATRANS: a -> relu(a*scale[k]+shift[k]) at staging; XEPI: += nf@Wemb+bemb;
// PART: per-(rowblock,col) BN partials; OUTF32: fp32 output (else bf16).
template <int NC, bool ATRANS, bool XEPI, bool PART, bool OUTF32>
__global__ __launch_bounds__(256, 2) void k_mgemm(
    const unsigned short* __restrict__ A, const unsigned short* __restrict__ Bt,
    const float* __restrict__ bias,
    const float* __restrict__ scale, const float* __restrict__ shift,
    const float* __restrict__ nf, const float* __restrict__ Wemb, const float* __restrict__ bemb,
    unsigned short* __restrict__ Cb, float* __restrict__ Cf,
    float* __restrict__ psum, float* __restrict__ psq) {
    __shared__ unsigned short As[64 * 256];
    __shared__ unsigned short Bs[64 * 256];
    __shared__ float sSc[HID];
    __shared__ float sSh[HID];
    __shared__ float sNf[64][6];
    __shared__ float sXW[6][HID];
    __shared__ float redS[2][64];
    __shared__ float redQ[2][64];

    int tid = threadIdx.x;
    int rb = blockIdx.x;
    int row0 = rb * 64;

    if (ATRANS) { sSc[tid] = scale[tid]; sSh[tid] = shift[tid]; }
    if (XEPI) {
        for (int t = tid; t < 6 * NC; t += 256) {
            int i = t / NC, cl = t % NC;
            sXW[i][cl] = Wemb[i * HID + cl];
        }
        if (tid < 64) {
            int n = row0 + tid;
#pragma unroll
            for (int i = 0; i < 6; ++i) sNf[tid][i] = (n < NNODES) ? nf[(size_t)n * 6 + i] : 0.f;
        }
    }
    if (ATRANS) __syncthreads();   // sSc/sSh consumed during A staging

    // ---- stage A tile 64x256 bf16 once (2048 x 16B chunks, 8 per thread) ----
#pragma unroll
    for (int i = 0; i < 8; ++i) {
        int g = i * 256 + tid;
        int row = g >> 5, kc = g & 31;
        uint4 v = *(const uint4*)(A + (size_t)(row0 + row) * 256 + kc * 8);
        if (ATRANS) {
            unsigned int w[4] = {v.x, v.y, v.z, v.w};
#pragma unroll
            for (int q = 0; q < 4; ++q) {
                int k0 = kc * 8 + q * 2;
                float f0 = b2f((unsigned short)(w[q] & 0xffffu));
                float f1 = b2f((unsigned short)(w[q] >> 16));
                f0 = fmaxf(fmaf(f0, sSc[k0], sSh[k0]), 0.f);
                f1 = fmaxf(fmaf(f1, sSc[k0 + 1], sSh[k0 + 1]), 0.f);
                w[q] = (unsigned int)f2b(f0) | ((unsigned int)f2b(f1) << 16);
            }
            v.x = w[0]; v.y = w[1]; v.z = w[2]; v.w = w[3];
        }
        int pkc = kc ^ (row & 7);
        *(uint4*)(&As[row * 256 + pkc * 8]) = v;
    }

    int w = tid >> 6, lane = tid & 63;
    int wm = w >> 1, wn = w & 1;            // 2x2 wave grid, each wave 32x32
    int lrow = lane & 15, lk = lane >> 4;

    for (int cb = 0; cb < NC / 64; ++cb) {
        int c0 = cb * 64;
        if (cb) __syncthreads();            // prev iter done reading Bs
        // ---- stage B^T tile 64x256 bf16 for this column block ----
#pragma unroll
        for (int i = 0; i < 8; ++i) {
            int g = i * 256 + tid;
            int row = g >> 5, kc = g & 31;
            uint4 v = *(const uint4*)(Bt + (size_t)(c0 + row) * 256 + kc * 8);
            int pkc = kc ^ (row & 7);
            *(uint4*)(&Bs[row * 256 + pkc * 8]) = v;
        }
        __syncthreads();                     // As (first iter) + Bs visible

        f32x4 acc[2][2] = {};
#pragma unroll
        for (int ks = 0; ks < 8; ++ks) {    // K = 8 x 32
            bf16x8 af[2], bfr[2];
#pragma unroll
            for (int fm = 0; fm < 2; ++fm) {
                int r = wm * 32 + fm * 16 + lrow;
                int kc = ks * 4 + lk;
                af[fm] = *(const bf16x8*)(&As[r * 256 + (kc ^ (r & 7)) * 8]);
            }
#pragma unroll
            for (int fn = 0; fn < 2; ++fn) {
                int r = wn * 32 + fn * 16 + lrow;
                int kc = ks * 4 + lk;
                bfr[fn] = *(const bf16x8*)(&Bs[r * 256 + (kc ^ (r & 7)) * 8]);
            }
#pragma unroll
            for (int fm = 0; fm < 2; ++fm)
#pragma unroll
                for (int fn = 0; fn < 2; ++fn)
                    acc[fm][fn] = __builtin_amdgcn_mfma_f32_16x16x32_bf16(af[fm], bfr[fn], acc[fm][fn], 0, 0, 0);
        }

        // ---- epilogue (C/D layout: col=lane&15, row=(lane>>4)*4+reg) ----
        float pS[2] = {0.f, 0.f}, pQ[2] = {0.f, 0.f};
#pragma unroll
        for (int fn = 0; fn < 2; ++fn) {
            int cl = wn * 32 + fn * 16 + lrow;
            int gc = c0 + cl;
            float bv = bias[gc];
            if (XEPI) bv += bemb[gc];
#pragma unroll
            for (int fm = 0; fm < 2; ++fm) {
#pragma unroll
                for (int r = 0; r < 4; ++r) {
                    int rl = wm * 32 + fm * 16 + lk * 4 + r;
                    int gr = row0 + rl;
                    float val = acc[fm][fn][r] + bv;
                    if (XEPI) {
#pragma unroll
                        for (int l = 0; l < 6; ++l) val = fmaf(sNf[rl][l], sXW[l][gc], val);
                    }
                    if (gr < NNODES) {
                        if (OUTF32) Cf[(size_t)gr * NC + gc] = val;
                        else        Cb[(size_t)gr * NC + gc] = f2b(val);
                        if (PART) { pS[fn] += val; pQ[fn] = fmaf(val, val, pQ[fn]); }
                    }
                }
            }
        }
        if (PART) {
#pragma unroll
            for (int fn = 0; fn < 2; ++fn) {
                float s = pS[fn], q = pQ[fn];
                s += __shfl_xor(s, 16); s += __shfl_xor(s, 32);
                q += __shfl_xor(q, 16); q += __shfl_xor(q, 32);
                if (lk == 0) {
                    int cl = wn * 32 + fn * 16 + lrow;
                    redS[wm][cl] = s;
                    redQ[wm][cl] = q;
                }
            }
            __syncthreads();
            if (tid < 64) {
                psum[(size_t)rb * HID + c0 + tid] = redS[0][tid] + redS[1][tid];
                psq [(size_t)rb * HID + c0 + tid] = redQ[0][tid] + redQ[1][tid];
            }
        }
    }
}

// ---------------- bf16 conv aggregation (layer 2): 1 wave per node, 4-deep MLP ------
__global__ __launch_bounds__(256) void k_agg(const int* __restrict__ row_ptr,
                                             const int2* __restrict__ csr_ew,
                                             const unsigned short* __restrict__ X,
                                             const float* __restrict__ dis,
                                             unsigned short* __restrict__ out) {
    int wid = threadIdx.x >> 6, lane = threadIdx.x & 63;
    int n = blockIdx.x * 4 + wid;
    if (n >= NNODES) return;
    int s = row_ptr[n], e = row_ptr[n + 1];
    float a0 = 0.f, a1 = 0.f, a2 = 0.f, a3 = 0.f;
    int i = s;
    // 4-way unroll: 4 independent 512B row gathers in flight per wave
    for (; i + 4 <= e; i += 4) {
        int2 e0 = csr_ew[i], e1 = csr_ew[i + 1], e2 = csr_ew[i + 2], e3 = csr_ew[i + 3];
        uint2 v0 = ((const uint2*)(X + (size_t)e0.x * HID))[lane];
        uint2 v1 = ((const uint2*)(X + (size_t)e1.x * HID))[lane];
        uint2 v2 = ((const uint2*)(X + (size_t)e2.x * HID))[lane];
        uint2 v3 = ((const uint2*)(X + (size_t)e3.x * HID))[lane];
        float w0 = __int_as_float(e0.y), w1 = __int_as_float(e1.y);
        float w2 = __int_as_float(e2.y), w3 = __int_as_float(e3.y);
        a0 = fmaf(w0, b2f((unsigned short)(v0.x & 0xffffu)), a0);
        a1 = fmaf(w0, b2f((unsigned short)(v0.x >> 16)), a1);
        a2 = fmaf(w0, b2f((unsigned short)(v0.y & 0xffffu)), a2);
        a3 = fmaf(w0, b2f((unsigned short)(v0.y >> 16)), a3);
        a0 = fmaf(w1, b2f((unsigned short)(v1.x & 0xffffu)), a0);
        a1 = fmaf(w1, b2f((unsigned short)(v1.x >> 16)), a1);
        a2 = fmaf(w1, b2f((unsigned short)(v1.y & 0xffffu)), a2);
        a3 = fmaf(w1, b2f((unsigned short)(v1.y >> 16)), a3);
        a0 = fmaf(w2, b2f((unsigned short)(v2.x & 0xffffu)), a0);
        a1 = fmaf(w2, b2f((unsigned short)(v2.x >> 16)), a1);
        a2 = fmaf(w2, b2f((unsigned short)(v2.y & 0xffffu)), a2);
        a3 = fmaf(w2, b2f((unsigned short)(v2.y >> 16)), a3);
        a0 = fmaf(w3, b2f((unsigned short)(v3.x & 0xffffu)), a0);
        a1 = fmaf(w3, b2f((unsigned short)(v3.x >> 16)), a1);
        a2 = fmaf(w3, b2f((unsigned short)(v3.y & 0xffffu)), a2);
        a3 = fmaf(w3, b2f((unsigned short)(v3.y >> 16)), a3);
    }
    for (; i < e; ++i) {
        int2 e0 = csr_ew[i];
        float w = __int_as_float(e0.y);
        uint2 v = ((const uint2*)(X + (size_t)e0.x * HID))[lane];
        a0 = fmaf(w, b2f((unsigned short)(v.x & 0xffffu)), a0);
        a1 = fmaf(w, b2f((unsigned short)(v.x >> 16)), a1);
        a2 = fmaf(w, b2f((unsigned short)(v.y & 0xffffu)), a2);
        a3 = fmaf(w, b2f((unsigned short)(v.y >> 16)), a3);
    }
    float r = dis[n];
    ushort4 o;
    o.x = f2b(a0 * r); o.y = f2b(a1 * r); o.z = f2b(a2 * r); o.w = f2b(a3 * r);
    ((ushort4*)(out + (size_t)n * HID))[lane] = o;
}

// ---------------- graph mean (sorted graph_ids, binary search) + classifier --------
__global__ __launch_bounds__(128) void k_mean_label(const float* __restrict__ Hout,
                                                    const int* __restrict__ gids,
                                                    const float* __restrict__ Wcls,
                                                    const float* __restrict__ bcls,
                                                    float* __restrict__ lab) {
    int g = blockIdx.x;
    int c = threadIdx.x;
    int lo = 0, hi = NNODES;
    while (lo < hi) { int mid = (lo + hi) >> 1; if (gids[mid] < g) lo = mid + 1; else hi = mid; }
    int s = lo;
    hi = NNODES;
    while (lo < hi) { int mid = (lo + hi) >> 1; if (gids[mid] < g + 1) lo = mid + 1; else hi = mid; }
    int e = lo;
    float acc = 0.f;
    for (int n = s; n < e; ++n) acc += Hout[(size_t)n * OUTD + c];
    int cnt = e - s;
    float y = acc / (float)max(cnt, 1);
    __shared__ float ys[OUTD];
    ys[c] = y;
    __syncthreads();
    if (c < NCLS) {
        float a = bcls[c];
        for (int k = 0; k < OUTD; ++k) a = fmaf(ys[k], Wcls[k * NCLS + c], a);
        lab[(size_t)g * NCLS + c] = a;
    }
}

// ---------------- host ----------------
extern "C" void kernel_launch(void* const* d_in, const int* in_sizes, int n_in,
                              void* d_out, int out_size, void* d_ws, size_t ws_size,
                              hipStream_t stream) {
    const float* nf   = (const float*)d_in[0];
    const int*   src  = (const int*)d_in[1];
    const int*   dst  = (const int*)d_in[2];
    const int*   gids = (const int*)d_in[3];
    const float* Wemb = (const float*)d_in[4];
    const float* bemb = (const float*)d_in[5];
    const float* Wc1  = (const float*)d_in[6];
    const float* bc1  = (const float*)d_in[7];
    const float* g1   = (const float*)d_in[8];
    const float* be1  = (const float*)d_in[9];
    const float* W2   = (const float*)d_in[10];
    const float* b2   = (const float*)d_in[11];
    const float* Wc2  = (const float*)d_in[12];
    const float* bc2  = (const float*)d_in[13];
    const float* g2   = (const float*)d_in[14];
    const float* be2  = (const float*)d_in[15];
    const float* W3   = (const float*)d_in[16];
    const float* b3   = (const float*)d_in[17];
    const float* Wcls = (const float*)d_in[18];
    const float* bcls = (const float*)d_in[19];

    float* out_h   = (float*)d_out;                 // [N, 128] fp32
    float* out_lab = out_h + (size_t)NNODES * OUTD; // [G, 60]

    // workspace bump allocator (floats, 256B granularity)
    float* ws = (float*)d_ws;
    size_t off = 0;
    auto take = [&](size_t n) { float* p = ws + off; off += (n + 63) & ~(size_t)63; return p; };
    unsigned short* actA = (unsigned short*)take((size_t)MPAD * HID / 2);  // bf16 [MPAD][256]
    unsigned short* actB = (unsigned short*)take((size_t)MPAD * HID / 2);  // bf16 [MPAD][256]
    unsigned short* Wt2  = (unsigned short*)take(HID * HID / 2);
    unsigned short* Wtc2 = (unsigned short*)take(HID * HID / 2);
    unsigned short* Wt3  = (unsigned short*)take(OUTD * HID / 2);
    int*   deg_out = (int*)take(NNODES);
    int*   deg_in  = (int*)take(NNODES);
    float* dout_is = take(NNODES);
    float* din_is  = take(NNODES);
    int*   row_ptr = (int*)take(NNODES + 1);
    int*   cursor  = (int*)take(NNODES);
    int2*  csr_ew  = (int2*)take((size_t)NEDGES * 2);
    float* t6      = take((size_t)NNODES * 6);
    float* u1      = take(NNODES);
    float* M1      = take(6 * HID);
    float* v1      = take(HID);
    float* psum    = take((size_t)NROWBLK * HID);
    float* psq     = take((size_t)NROWBLK * HID);
    float* scale1  = take(HID);
    float* shift1  = take(HID);
    float* scale2  = take(HID);
    float* shift2  = take(HID);
    int*   bsum    = (int*)take(128);
    double* bn_tmp = (double*)take(2 * 2 * REDBLK * HID);

    // 1. zero degree arrays
    k_zero_int<<<(2 * 100032 + 255) / 256, 256, 0, stream>>>(deg_out, 2 * 100032);
    // 2. degrees
    k_deg<<<(NEDGES + 255) / 256, 256, 0, stream>>>(src, dst, deg_out, deg_in);
    // 3. isqrt
    k_isqrt<<<(NNODES + 255) / 256, 256, 0, stream>>>(deg_out, deg_in, dout_is, din_is);
    // 4. CSR: hierarchical scan + scatter (packed int2 edge records)
    k_blk_sum<<<NSCANBLK, 256, 0, stream>>>(deg_in, bsum);
    k_scan_bsum<<<1, 64, 0, stream>>>(bsum);
    k_scan_local<<<NSCANBLK, 1024, 0, stream>>>(deg_in, bsum, row_ptr, cursor);
    k_scatter<<<(NEDGES + 255) / 256, 256, 0, stream>>>(src, dst, dout_is, cursor, csr_ew);
    // 5. weight conversion + M1/v1
    k_wconv<<<(HID * HID + 255) / 256, 256, 0, stream>>>(W2, Wt2, HID, HID);
    k_wconv<<<(HID * HID + 255) / 256, 256, 0, stream>>>(Wc2, Wtc2, HID, HID);
    k_wconv<<<(HID * OUTD + 255) / 256, 256, 0, stream>>>(W3, Wt3, HID, OUTD);
    k_small_mm<<<7, 256, 0, stream>>>(Wemb, bemb, Wc1, M1, v1);
    // 6. 6-dim aggregation
    k_agg6<<<(NNODES + 255) / 256, 256, 0, stream>>>(row_ptr, csr_ew, nf, t6, u1);
    // 7. fused layer 1 -> actA (h_pre1 bf16) + BN1 partials
    k_layer1<<<NROWBLK, 256, 0, stream>>>(nf, Wemb, bemb, M1, v1, bc1, t6, u1, din_is,
                                          actA, psum, psq);
    // 8. BN1 scale/shift
    k_bn_part<<<REDBLK, 256, 0, stream>>>(psum, psq, bn_tmp);
    k_bn_final<<<1, 256, 0, stream>>>(bn_tmp, g1, be1, scale1, shift1);
    // 9. h2 = relu(bn1(h_pre1)) @ W2 + b2 -> actB (bf16)
    k_mgemm<HID, true, false, false, false><<<NROWBLK, 256, 0, stream>>>(
        actA, Wt2, b2, scale1, shift1, nullptr, nullptr, nullptr, actB, nullptr, nullptr, nullptr);
    // 10. A2 = conv-aggregate(h2) -> actA (bf16)
    k_agg<<<NNODES / 4, 256, 0, stream>>>(row_ptr, csr_ew, actB, din_is, actA);
    // 11. h_pre2 = x + A2 @ Wc2 + bc2 -> actB (bf16) + BN2 partials
    k_mgemm<HID, false, true, true, false><<<NROWBLK, 256, 0, stream>>>(
        actA, Wtc2, bc2, nullptr, nullptr, nf, Wemb, bemb, actB, nullptr, psum, psq);
    // 12. BN2 scale/shift
    k_bn_part<<<REDBLK, 256, 0, stream>>>(psum, psq, bn_tmp);
    k_bn_final<<<1, 256, 0, stream>>>(bn_tmp, g2, be2, scale2, shift2);
    // 13. h_out = relu(bn2(h_pre2)) @ W3 + b3 -> d_out fp32
    k_mgemm<OUTD, true, false, false, true><<<NROWBLK, 256, 0, stream>>>(
        actB, Wt3, b3, scale2, shift2, nullptr, nullptr, nullptr, nullptr, out_h, nullptr, nullptr);
    // 14. graph mean + classifier
    k_mean_label<<<NGRAPHS, OUTD, 0, stream>>>(out_h, gids, Wcls, bcls, out_lab);
}

// Round 6
// 723.998 us; speedup vs baseline: 1.5923x; 1.0768x over previous
//
#include <hip/hip_runtime.h>

#define NNODES 100000
#define MPAD   100032          // 1563 * 64
#define NEDGES 1600000
#define NGRAPHS 2000
#define HID 256
#define OUTD 128
#define NCLS 60
#define BN_EPS 1e-5f
#define NROWBLK 1563   // ceil(NNODES/64)
#define NSCANBLK 98    // ceil(NNODES/1024)
#define REDBLK 32

typedef __attribute__((ext_vector_type(8))) short bf16x8;
typedef __attribute__((ext_vector_type(4))) float f32x4;

__device__ __forceinline__ float b2f(unsigned short b) {
    unsigned int u = ((unsigned int)b) << 16;
    return __builtin_bit_cast(float, u);
}
__device__ __forceinline__ unsigned short f2b(float f) {
    unsigned int u = __builtin_bit_cast(unsigned int, f);
    u = (u + 0x7FFFu + ((u >> 16) & 1u)) >> 16;     // RNE
    return (unsigned short)u;
}

// ---------------- utility ----------------
__global__ void k_zero_int(int* __restrict__ p, int n) {
    int i = blockIdx.x * blockDim.x + threadIdx.x;
    if (i < n) p[i] = 0;
}

// ---------------- degrees + local position (2 atomics/edge, was 3) ----------------
// lpos[e] = old value of din[dst[e]] -> unique 0-based slot within dst's segment
__global__ void k_deg2(const int* __restrict__ src, const int* __restrict__ dst,
                       int* __restrict__ dout, int* __restrict__ din,
                       int* __restrict__ lpos) {
    int e = blockIdx.x * blockDim.x + threadIdx.x;
    if (e < NEDGES) {
        atomicAdd(&dout[src[e]], 1);
        lpos[e] = atomicAdd(&din[dst[e]], 1);
    }
}

__global__ void k_isqrt(const int* __restrict__ dout, const int* __restrict__ din,
                        float* __restrict__ dos, float* __restrict__ dis) {
    int i = blockIdx.x * blockDim.x + threadIdx.x;
    if (i < NNODES) {
        int a = dout[i], b = din[i];
        dos[i] = a > 0 ? 1.0f / sqrtf((float)a) : 0.0f;
        dis[i] = b > 0 ? 1.0f / sqrtf((float)b) : 0.0f;
    }
}

// ---------------- hierarchical exclusive scan of din -> row_ptr ----------
__global__ void k_blk_sum(const int* __restrict__ deg, int* __restrict__ bsum) {
    __shared__ int red[256];
    int blk = blockIdx.x, tid = threadIdx.x;
    int base = blk * 1024;
    int s = 0;
#pragma unroll
    for (int j = 0; j < 4; ++j) {
        int i = base + tid + j * 256;
        if (i < NNODES) s += deg[i];
    }
    red[tid] = s;
    __syncthreads();
    for (int off = 128; off > 0; off >>= 1) {
        if (tid < off) red[tid] += red[tid + off];
        __syncthreads();
    }
    if (tid == 0) bsum[blk] = red[0];
}

__global__ void k_scan_bsum(int* __restrict__ bsum) {
    if (threadIdx.x == 0) {
        int acc = 0;
        for (int i = 0; i < NSCANBLK; ++i) { int v = bsum[i]; bsum[i] = acc; acc += v; }
    }
}

__global__ void k_scan_local(const int* __restrict__ deg, const int* __restrict__ bsum,
                             int* __restrict__ row_ptr) {
    __shared__ int buf[1024];
    int blk = blockIdx.x, tid = threadIdx.x;
    int i = blk * 1024 + tid;
    int v = (i < NNODES) ? deg[i] : 0;
    buf[tid] = v;
    __syncthreads();
    for (int off = 1; off < 1024; off <<= 1) {
        int t = (tid >= off) ? buf[tid - off] : 0;
        __syncthreads();
        buf[tid] += t;
        __syncthreads();
    }
    int inc = buf[tid] + bsum[blk];
    if (i < NNODES) row_ptr[i + 1] = inc;
    if (i == 0) row_ptr[0] = 0;
}

// ---------------- atomic-free edge placement ----------------
__global__ void k_place(const int* __restrict__ src, const int* __restrict__ dst,
                        const int* __restrict__ lpos, const int* __restrict__ row_ptr,
                        const float* __restrict__ dos, int2* __restrict__ csr_ew) {
    int e = blockIdx.x * blockDim.x + threadIdx.x;
    if (e < NEDGES) {
        int s = src[e];
        csr_ew[row_ptr[dst[e]] + lpos[e]] = make_int2(s, __float_as_int(dos[s]));
    }
}

// ---------------- weight convert: W[K][N] f32 -> Wt[N][K] bf16 ----------------
__global__ void k_wconv(const float* __restrict__ W, unsigned short* __restrict__ Wt,
                        int K, int N) {
    int idx = blockIdx.x * 256 + threadIdx.x;
    if (idx >= N * K) return;
    int n = idx / K, k = idx - n * K;
    Wt[idx] = f2b(W[(size_t)k * N + n]);
}

// ---------------- M1 = W_emb @ Wc1 (6x256), v1 = b_emb @ Wc1 (256) ----------------
__global__ void k_small_mm(const float* __restrict__ Wemb, const float* __restrict__ bemb,
                           const float* __restrict__ Wc1, float* __restrict__ M1,
                           float* __restrict__ v1) {
    int c = threadIdx.x;
    int bi = blockIdx.x;
    float acc = 0.f;
    if (bi < 6) {
        for (int k = 0; k < HID; ++k) acc = fmaf(Wemb[bi * HID + k], Wc1[k * HID + c], acc);
        M1[bi * HID + c] = acc;
    } else {
        for (int k = 0; k < HID; ++k) acc = fmaf(bemb[k], Wc1[k * HID + c], acc);
        v1[c] = acc;
    }
}

// ---------------- 6-dim edge aggregation (collapsed layer-1 conv) ----------------
__global__ void k_agg6(const int* __restrict__ row_ptr, const int2* __restrict__ csr_ew,
                       const float* __restrict__ nf,
                       float* __restrict__ t6, float* __restrict__ u1) {
    int n = blockIdx.x * blockDim.x + threadIdx.x;
    if (n >= NNODES) return;
    float a0 = 0, a1 = 0, a2 = 0, a3 = 0, a4 = 0, a5 = 0, au = 0;
    int s = row_ptr[n], e = row_ptr[n + 1];
    int i = s;
    for (; i + 2 <= e; i += 2) {
        int2 g0 = csr_ew[i], g1 = csr_ew[i + 1];
        float w0 = __int_as_float(g0.y), w1 = __int_as_float(g1.y);
        const float* p0 = nf + (size_t)g0.x * 6;
        const float* p1 = nf + (size_t)g1.x * 6;
        a0 = fmaf(w0, p0[0], a0); a1 = fmaf(w0, p0[1], a1); a2 = fmaf(w0, p0[2], a2);
        a3 = fmaf(w0, p0[3], a3); a4 = fmaf(w0, p0[4], a4); a5 = fmaf(w0, p0[5], a5);
        au += w0;
        a0 = fmaf(w1, p1[0], a0); a1 = fmaf(w1, p1[1], a1); a2 = fmaf(w1, p1[2], a2);
        a3 = fmaf(w1, p1[3], a3); a4 = fmaf(w1, p1[4], a4); a5 = fmaf(w1, p1[5], a5);
        au += w1;
    }
    for (; i < e; ++i) {
        int2 g0 = csr_ew[i];
        float w = __int_as_float(g0.y);
        const float* p = nf + (size_t)g0.x * 6;
        a0 = fmaf(w, p[0], a0); a1 = fmaf(w, p[1], a1); a2 = fmaf(w, p[2], a2);
        a3 = fmaf(w, p[3], a3); a4 = fmaf(w, p[4], a4); a5 = fmaf(w, p[5], a5);
        au += w;
    }
    float* t = t6 + (size_t)n * 6;
    t[0] = a0; t[1] = a1; t[2] = a2; t[3] = a3; t[4] = a4; t[5] = a5;
    u1[n] = au;
}

// ---------------- fused layer 1 -> bf16 h_pre1 + fp32 BN partials ----------------
__global__ __launch_bounds__(256) void k_layer1(
    const float* __restrict__ nf, const float* __restrict__ Wemb, const float* __restrict__ bemb,
    const float* __restrict__ M1, const float* __restrict__ v1, const float* __restrict__ bc1,
    const float* __restrict__ t6, const float* __restrict__ u1, const float* __restrict__ dis,
    unsigned short* __restrict__ H, float* __restrict__ psum, float* __restrict__ psq) {
    __shared__ float s_nf[64][6];
    __shared__ float s_t6[64][6];
    __shared__ float s_u[64];
    __shared__ float s_r[64];
    int blk = blockIdx.x;
    int n0 = blk * 64;
    int tid = threadIdx.x;
    for (int t = tid; t < 384; t += 256) {
        int nl = t / 6, i = t % 6;
        int n = n0 + nl;
        s_nf[nl][i] = (n < NNODES) ? nf[(size_t)n * 6 + i] : 0.f;
        s_t6[nl][i] = (n < NNODES) ? t6[(size_t)n * 6 + i] : 0.f;
    }
    if (tid < 64) {
        int n = n0 + tid;
        s_u[tid] = (n < NNODES) ? u1[n] : 0.f;
        s_r[tid] = (n < NNODES) ? dis[n] : 0.f;
    }
    int c = tid;
    float wc[6], mc[6];
#pragma unroll
    for (int i = 0; i < 6; ++i) { wc[i] = Wemb[i * HID + c]; mc[i] = M1[i * HID + c]; }
    float v1c = v1[c];
    float bsum = bemb[c] + bc1[c];
    __syncthreads();
    float ps = 0.f, pq = 0.f;
    int nmax = min(64, NNODES - n0);
    for (int nl = 0; nl < nmax; ++nl) {
        float nfd = 0.f, td = 0.f;
#pragma unroll
        for (int i = 0; i < 6; ++i) {
            nfd = fmaf(s_nf[nl][i], wc[i], nfd);
            td = fmaf(s_t6[nl][i], mc[i], td);
        }
        float val = nfd + s_r[nl] * (td + s_u[nl] * v1c) + bsum;
        H[(size_t)(n0 + nl) * HID + c] = f2b(val);
        ps += val;
        pq = fmaf(val, val, pq);
    }
    for (int nl = nmax; nl < 64; ++nl) H[(size_t)(n0 + nl) * HID + c] = 0;  // zero pad rows
    psum[blk * HID + c] = ps;
    psq[blk * HID + c] = pq;
}

// ---------------- BN two-stage reduce -> scale/shift ----------------
__global__ void k_bn_part(const float* __restrict__ psum, const float* __restrict__ psq,
                          double* __restrict__ tmp) {
    int c = threadIdx.x;
    int s = blockIdx.x;
    double a = 0.0, b = 0.0;
    for (int bb = s; bb < NROWBLK; bb += REDBLK) {
        a += psum[bb * HID + c];
        b += psq[bb * HID + c];
    }
    tmp[s * HID + c] = a;
    tmp[(REDBLK + s) * HID + c] = b;
}

__global__ void k_bn_final(const double* __restrict__ tmp, const float* __restrict__ g,
                           const float* __restrict__ be, float* __restrict__ scale,
                           float* __restrict__ shift) {
    int c = threadIdx.x;
    double s = 0.0, q = 0.0;
    for (int i = 0; i < REDBLK; ++i) { s += tmp[i * HID + c]; q += tmp[(REDBLK + i) * HID + c]; }
    double mu = s / (double)NNODES;
    double var = q / (double)NNODES - mu * mu;
    if (var < 0.0) var = 0.0;
    double inv = 1.0 / sqrt(var + (double)BN_EPS);
    float sc = (float)((double)g[c] * inv);
    scale[c] = sc;
    shift[c] = be[c] - (float)mu * sc;
}

// ================= bf16 MFMA GEMM, A-panel reused across all column blocks =========
template <int NC, bool ATRANS, bool XEPI, bool PART, bool OUTF32>
__global__ __launch_bounds__(256, 2) void k_mgemm(
    const unsigned short* __restrict__ A, const unsigned short* __restrict__ Bt,
    const float* __restrict__ bias,
    const float* __restrict__ scale, const float* __restrict__ shift,
    const float* __restrict__ nf, const float* __restrict__ Wemb, const float* __restrict__ bemb,
    unsigned short* __restrict__ Cb, float* __restrict__ Cf,
    float* __restrict__ psum, float* __restrict__ psq) {
    __shared__ unsigned short As[64 * 256];
    __shared__ unsigned short Bs[64 * 256];
    __shared__ float sSc[HID];
    __shared__ float sSh[HID];
    __shared__ float sNf[64][6];
    __shared__ float sXW[6][HID];
    __shared__ float redS[2][64];
    __shared__ float redQ[2][64];

    int tid = threadIdx.x;
    int rb = blockIdx.x;
    int row0 = rb * 64;

    if (ATRANS) { sSc[tid] = scale[tid]; sSh[tid] = shift[tid]; }
    if (XEPI) {
        for (int t = tid; t < 6 * NC; t += 256) {
            int i = t / NC, cl = t % NC;
            sXW[i][cl] = Wemb[i * HID + cl];
        }
        if (tid < 64) {
            int n = row0 + tid;
#pragma unroll
            for (int i = 0; i < 6; ++i) sNf[tid][i] = (n < NNODES) ? nf[(size_t)n * 6 + i] : 0.f;
        }
    }
    if (ATRANS) __syncthreads();   // sSc/sSh consumed during A staging

    // ---- stage A tile 64x256 bf16 once (2048 x 16B chunks, 8 per thread) ----
#pragma unroll
    for (int i = 0; i < 8; ++i) {
        int g = i * 256 + tid;
        int row = g >> 5, kc = g & 31;
        uint4 v = *(const uint4*)(A + (size_t)(row0 + row) * 256 + kc * 8);
        if (ATRANS) {
            unsigned int w[4] = {v.x, v.y, v.z, v.w};
#pragma unroll
            for (int q = 0; q < 4; ++q) {
                int k0 = kc * 8 + q * 2;
                float f0 = b2f((unsigned short)(w[q] & 0xffffu));
                float f1 = b2f((unsigned short)(w[q] >> 16));
                f0 = fmaxf(fmaf(f0, sSc[k0], sSh[k0]), 0.f);
                f1 = fmaxf(fmaf(f1, sSc[k0 + 1], sSh[k0 + 1]), 0.f);
                w[q] = (unsigned int)f2b(f0) | ((unsigned int)f2b(f1) << 16);
            }
            v.x = w[0]; v.y = w[1]; v.z = w[2]; v.w = w[3];
        }
        int pkc = kc ^ (row & 7);
        *(uint4*)(&As[row * 256 + pkc * 8]) = v;
    }

    int w = tid >> 6, lane = tid & 63;
    int wm = w >> 1, wn = w & 1;            // 2x2 wave grid, each wave 32x32
    int lrow = lane & 15, lk = lane >> 4;

    for (int cb = 0; cb < NC / 64; ++cb) {
        int c0 = cb * 64;
        if (cb) __syncthreads();            // prev iter done reading Bs
        // ---- stage B^T tile 64x256 bf16 for this column block ----
#pragma unroll
        for (int i = 0; i < 8; ++i) {
            int g = i * 256 + tid;
            int row = g >> 5, kc = g & 31;
            uint4 v = *(const uint4*)(Bt + (size_t)(c0 + row) * 256 + kc * 8);
            int pkc = kc ^ (row & 7);
            *(uint4*)(&Bs[row * 256 + pkc * 8]) = v;
        }
        __syncthreads();

        f32x4 acc[2][2] = {};
#pragma unroll
        for (int ks = 0; ks < 8; ++ks) {    // K = 8 x 32
            bf16x8 af[2], bfr[2];
#pragma unroll
            for (int fm = 0; fm < 2; ++fm) {
                int r = wm * 32 + fm * 16 + lrow;
                int kc = ks * 4 + lk;
                af[fm] = *(const bf16x8*)(&As[r * 256 + (kc ^ (r & 7)) * 8]);
            }
#pragma unroll
            for (int fn = 0; fn < 2; ++fn) {
                int r = wn * 32 + fn * 16 + lrow;
                int kc = ks * 4 + lk;
                bfr[fn] = *(const bf16x8*)(&Bs[r * 256 + (kc ^ (r & 7)) * 8]);
            }
#pragma unroll
            for (int fm = 0; fm < 2; ++fm)
#pragma unroll
                for (int fn = 0; fn < 2; ++fn)
                    acc[fm][fn] = __builtin_amdgcn_mfma_f32_16x16x32_bf16(af[fm], bfr[fn], acc[fm][fn], 0, 0, 0);
        }

        // ---- epilogue (C/D layout: col=lane&15, row=(lane>>4)*4+reg) ----
        float pS[2] = {0.f, 0.f}, pQ[2] = {0.f, 0.f};
#pragma unroll
        for (int fn = 0; fn < 2; ++fn) {
            int cl = wn * 32 + fn * 16 + lrow;
            int gc = c0 + cl;
            float bv = bias[gc];
            if (XEPI) bv += bemb[gc];
#pragma unroll
            for (int fm = 0; fm < 2; ++fm) {
#pragma unroll
                for (int r = 0; r < 4; ++r) {
                    int rl = wm * 32 + fm * 16 + lk * 4 + r;
                    int gr = row0 + rl;
                    float val = acc[fm][fn][r] + bv;
                    if (XEPI) {
#pragma unroll
                        for (int l = 0; l < 6; ++l) val = fmaf(sNf[rl][l], sXW[l][gc], val);
                    }
                    if (gr < NNODES) {
                        if (OUTF32) Cf[(size_t)gr * NC + gc] = val;
                        else        Cb[(size_t)gr * NC + gc] = f2b(val);
                        if (PART) { pS[fn] += val; pQ[fn] = fmaf(val, val, pQ[fn]); }
                    }
                }
            }
        }
        if (PART) {
#pragma unroll
            for (int fn = 0; fn < 2; ++fn) {
                float s = pS[fn], q = pQ[fn];
                s += __shfl_xor(s, 16); s += __shfl_xor(s, 32);
                q += __shfl_xor(q, 16); q += __shfl_xor(q, 32);
                if (lk == 0) {
                    int cl = wn * 32 + fn * 16 + lrow;
                    redS[wm][cl] = s;
                    redQ[wm][cl] = q;
                }
            }
            __syncthreads();
            if (tid < 64) {
                psum[(size_t)rb * HID + c0 + tid] = redS[0][tid] + redS[1][tid];
                psq [(size_t)rb * HID + c0 + tid] = redQ[0][tid] + redQ[1][tid];
            }
        }
    }
}

// ---------------- bf16 conv aggregation: 1 wave/node, 2 edges/wave-iter -------------
// Each 32-lane half-wave reads a full 512B row (uint4 = 16B/lane); halves combine
// via one shfl_xor(32) at the end. 4x unroll -> 8 edges (8 gathers) in flight.
#define ACC8(vv, ww) { \
    a[0] = fmaf(ww, b2f((unsigned short)(vv.x & 0xffffu)), a[0]); \
    a[1] = fmaf(ww, b2f((unsigned short)(vv.x >> 16)),     a[1]); \
    a[2] = fmaf(ww, b2f((unsigned short)(vv.y & 0xffffu)), a[2]); \
    a[3] = fmaf(ww, b2f((unsigned short)(vv.y >> 16)),     a[3]); \
    a[4] = fmaf(ww, b2f((unsigned short)(vv.z & 0xffffu)), a[4]); \
    a[5] = fmaf(ww, b2f((unsigned short)(vv.z >> 16)),     a[5]); \
    a[6] = fmaf(ww, b2f((unsigned short)(vv.w & 0xffffu)), a[6]); \
    a[7] = fmaf(ww, b2f((unsigned short)(vv.w >> 16)),     a[7]); }

__global__ __launch_bounds__(256) void k_agg(const int* __restrict__ row_ptr,
                                             const int2* __restrict__ csr_ew,
                                             const unsigned short* __restrict__ X,
                                             const float* __restrict__ dis,
                                             unsigned short* __restrict__ out) {
    int wid = threadIdx.x >> 6, lane = threadIdx.x & 63;
    int half = lane >> 5, l32 = lane & 31;
    int n = blockIdx.x * 4 + wid;
    if (n >= NNODES) return;
    int s = row_ptr[n], e = row_ptr[n + 1];
    float a[8] = {0.f, 0.f, 0.f, 0.f, 0.f, 0.f, 0.f, 0.f};
    int i = s;
    for (; i + 8 <= e; i += 8) {
        int2 e0 = csr_ew[i + half];
        int2 e1 = csr_ew[i + 2 + half];
        int2 e2 = csr_ew[i + 4 + half];
        int2 e3 = csr_ew[i + 6 + half];
        uint4 v0 = ((const uint4*)(X + (size_t)e0.x * HID))[l32];
        uint4 v1 = ((const uint4*)(X + (size_t)e1.x * HID))[l32];
        uint4 v2 = ((const uint4*)(X + (size_t)e2.x * HID))[l32];
        uint4 v3 = ((const uint4*)(X + (size_t)e3.x * HID))[l32];
        float w0 = __int_as_float(e0.y), w1 = __int_as_float(e1.y);
        float w2 = __int_as_float(e2.y), w3 = __int_as_float(e3.y);
        ACC8(v0, w0) ACC8(v1, w1) ACC8(v2, w2) ACC8(v3, w3)
    }
    for (; i + 2 <= e; i += 2) {
        int2 e0 = csr_ew[i + half];
        uint4 v0 = ((const uint4*)(X + (size_t)e0.x * HID))[l32];
        float w0 = __int_as_float(e0.y);
        ACC8(v0, w0)
    }
    if (i < e && half == 0) {       // odd leftover edge: half 0 only
        int2 e0 = csr_ew[i];
        uint4 v0 = ((const uint4*)(X + (size_t)e0.x * HID))[l32];
        float w0 = __int_as_float(e0.y);
        ACC8(v0, w0)
    }
#pragma unroll
    for (int j = 0; j < 8; ++j) a[j] += __shfl_xor(a[j], 32);
    if (half == 0) {
        float r = dis[n];
        uint4 o;
        o.x = (unsigned)f2b(a[0] * r) | ((unsigned)f2b(a[1] * r) << 16);
        o.y = (unsigned)f2b(a[2] * r) | ((unsigned)f2b(a[3] * r) << 16);
        o.z = (unsigned)f2b(a[4] * r) | ((unsigned)f2b(a[5] * r) << 16);
        o.w = (unsigned)f2b(a[6] * r) | ((unsigned)f2b(a[7] * r) << 16);
        ((uint4*)(out + (size_t)n * HID))[l32] = o;
    }
}

// ---------------- graph mean (sorted graph_ids, binary search) + classifier --------
__global__ __launch_bounds__(128) void k_mean_label(const float* __restrict__ Hout,
                                                    const int* __restrict__ gids,
                                                    const float* __restrict__ Wcls,
                                                    const float* __restrict__ bcls,
                                                    float* __restrict__ lab) {
    int g = blockIdx.x;
    int c = threadIdx.x;
    int lo = 0, hi = NNODES;
    while (lo < hi) { int mid = (lo + hi) >> 1; if (gids[mid] < g) lo = mid + 1; else hi = mid; }
    int s = lo;
    hi = NNODES;
    while (lo < hi) { int mid = (lo + hi) >> 1; if (gids[mid] < g + 1) lo = mid + 1; else hi = mid; }
    int e = lo;
    float acc = 0.f;
    for (int n = s; n < e; ++n) acc += Hout[(size_t)n * OUTD + c];
    int cnt = e - s;
    float y = acc / (float)max(cnt, 1);
    __shared__ float ys[OUTD];
    ys[c] = y;
    __syncthreads();
    if (c < NCLS) {
        float a = bcls[c];
        for (int k = 0; k < OUTD; ++k) a = fmaf(ys[k], Wcls[k * NCLS + c], a);
        lab[(size_t)g * NCLS + c] = a;
    }
}

// ---------------- host ----------------
extern "C" void kernel_launch(void* const* d_in, const int* in_sizes, int n_in,
                              void* d_out, int out_size, void* d_ws, size_t ws_size,
                              hipStream_t stream) {
    const float* nf   = (const float*)d_in[0];
    const int*   src  = (const int*)d_in[1];
    const int*   dst  = (const int*)d_in[2];
    const int*   gids = (const int*)d_in[3];
    const float* Wemb = (const float*)d_in[4];
    const float* bemb = (const float*)d_in[5];
    const float* Wc1  = (const float*)d_in[6];
    const float* bc1  = (const float*)d_in[7];
    const float* g1   = (const float*)d_in[8];
    const float* be1  = (const float*)d_in[9];
    const float* W2   = (const float*)d_in[10];
    const float* b2   = (const float*)d_in[11];
    const float* Wc2  = (const float*)d_in[12];
    const float* bc2  = (const float*)d_in[13];
    const float* g2   = (const float*)d_in[14];
    const float* be2  = (const float*)d_in[15];
    const float* W3   = (const float*)d_in[16];
    const float* b3   = (const float*)d_in[17];
    const float* Wcls = (const float*)d_in[18];
    const float* bcls = (const float*)d_in[19];

    float* out_h   = (float*)d_out;                 // [N, 128] fp32
    float* out_lab = out_h + (size_t)NNODES * OUTD; // [G, 60]

    // workspace bump allocator (floats, 256B granularity)
    float* ws = (float*)d_ws;
    size_t off = 0;
    auto take = [&](size_t n) { float* p = ws + off; off += (n + 63) & ~(size_t)63; return p; };
    unsigned short* actA = (unsigned short*)take((size_t)MPAD * HID / 2);  // bf16 [MPAD][256]
    unsigned short* actB = (unsigned short*)take((size_t)MPAD * HID / 2);  // bf16 [MPAD][256]
    unsigned short* Wt2  = (unsigned short*)take(HID * HID / 2);
    unsigned short* Wtc2 = (unsigned short*)take(HID * HID / 2);
    unsigned short* Wt3  = (unsigned short*)take(OUTD * HID / 2);
    int*   deg_out = (int*)take(NNODES);
    int*   deg_in  = (int*)take(NNODES);
    float* dout_is = take(NNODES);
    float* din_is  = take(NNODES);
    int*   row_ptr = (int*)take(NNODES + 1);
    int*   lpos    = (int*)take(NEDGES);
    int2*  csr_ew  = (int2*)take((size_t)NEDGES * 2);
    float* t6      = take((size_t)NNODES * 6);
    float* u1      = take(NNODES);
    float* M1      = take(6 * HID);
    float* v1      = take(HID);
    float* psum    = take((size_t)NROWBLK * HID);
    float* psq     = take((size_t)NROWBLK * HID);
    float* scale1  = take(HID);
    float* shift1  = take(HID);
    float* scale2  = take(HID);
    float* shift2  = take(HID);
    int*   bsum    = (int*)take(128);
    double* bn_tmp = (double*)take(2 * 2 * REDBLK * HID);

    // 1. zero degree arrays (deg_out/deg_in contiguous)
    k_zero_int<<<(2 * 100032 + 255) / 256, 256, 0, stream>>>(deg_out, 2 * 100032);
    // 2. degrees + local positions (2 atomics/edge)
    k_deg2<<<(NEDGES + 255) / 256, 256, 0, stream>>>(src, dst, deg_out, deg_in, lpos);
    // 3. isqrt
    k_isqrt<<<(NNODES + 255) / 256, 256, 0, stream>>>(deg_out, deg_in, dout_is, din_is);
    // 4. CSR: hierarchical scan + atomic-free placement
    k_blk_sum<<<NSCANBLK, 256, 0, stream>>>(deg_in, bsum);
    k_scan_bsum<<<1, 64, 0, stream>>>(bsum);
    k_scan_local<<<NSCANBLK, 1024, 0, stream>>>(deg_in, bsum, row_ptr);
    k_place<<<(NEDGES + 255) / 256, 256, 0, stream>>>(src, dst, lpos, row_ptr, dout_is, csr_ew);
    // 5. weight conversion + M1/v1
    k_wconv<<<(HID * HID + 255) / 256, 256, 0, stream>>>(W2, Wt2, HID, HID);
    k_wconv<<<(HID * HID + 255) / 256, 256, 0, stream>>>(Wc2, Wtc2, HID, HID);
    k_wconv<<<(HID * OUTD + 255) / 256, 256, 0, stream>>>(W3, Wt3, HID, OUTD);
    k_small_mm<<<7, 256, 0, stream>>>(Wemb, bemb, Wc1, M1, v1);
    // 6. 6-dim aggregation
    k_agg6<<<(NNODES + 255) / 256, 256, 0, stream>>>(row_ptr, csr_ew, nf, t6, u1);
    // 7. fused layer 1 -> actA (h_pre1 bf16) + BN1 partials
    k_layer1<<<NROWBLK, 256, 0, stream>>>(nf, Wemb, bemb, M1, v1, bc1, t6, u1, din_is,
                                          actA, psum, psq);
    // 8. BN1 scale/shift
    k_bn_part<<<REDBLK, 256, 0, stream>>>(psum, psq, bn_tmp);
    k_bn_final<<<1, 256, 0, stream>>>(bn_tmp, g1, be1, scale1, shift1);
    // 9. h2 = relu(bn1(h_pre1)) @ W2 + b2 -> actB (bf16)
    k_mgemm<HID, true, false, false, false><<<NROWBLK, 256, 0, stream>>>(
        actA, Wt2, b2, scale1, shift1, nullptr, nullptr, nullptr, actB, nullptr, nullptr, nullptr);
    // 10. A2 = conv-aggregate(h2) -> actA (bf16)
    k_agg<<<NNODES / 4, 256, 0, stream>>>(row_ptr, csr_ew, actB, din_is, actA);
    // 11. h_pre2 = x + A2 @ Wc2 + bc2 -> actB (bf16) + BN2 partials
    k_mgemm<HID, false, true, true, false><<<NROWBLK, 256, 0, stream>>>(
        actA, Wtc2, bc2, nullptr, nullptr, nf, Wemb, bemb, actB, nullptr, psum, psq);
    // 12. BN2 scale/shift
    k_bn_part<<<REDBLK, 256, 0, stream>>>(psum, psq, bn_tmp);
    k_bn_final<<<1, 256, 0, stream>>>(bn_tmp, g2, be2, scale2, shift2);
    // 13. h_out = relu(bn2(h_pre2)) @ W3 + b3 -> d_out fp32
    k_mgemm<OUTD, true, false, false, true><<<NROWBLK, 256, 0, stream>>>(
        actB, Wt3, b3, scale2, shift2, nullptr, nullptr, nullptr, nullptr, out_h, nullptr, nullptr);
    // 14. graph mean + classifier
    k_mean_label<<<NGRAPHS, OUTD, 0, stream>>>(out_h, gids, Wcls, bcls, out_lab);
}

// Round 7
// 720.803 us; speedup vs baseline: 1.5993x; 1.0044x over previous
//
#include <hip/hip_runtime.h>

#define NNODES 100000
#define MPAD   100032          // 1563 * 64
#define NEDGES 1600000
#define NGRAPHS 2000
#define HID 256
#define OUTD 128
#define NCLS 60
#define BN_EPS 1e-5f
#define NROWBLK 1563   // ceil(NNODES/64)
#define NSCANBLK 98    // ceil(NNODES/1024)
#define REDBLK 32

typedef __attribute__((ext_vector_type(8))) short bf16x8;
typedef __attribute__((ext_vector_type(4))) float f32x4;

__device__ __forceinline__ float b2f(unsigned short b) {
    unsigned int u = ((unsigned int)b) << 16;
    return __builtin_bit_cast(float, u);
}
__device__ __forceinline__ unsigned short f2b(float f) {
    unsigned int u = __builtin_bit_cast(unsigned int, f);
    u = (u + 0x7FFFu + ((u >> 16) & 1u)) >> 16;     // RNE
    return (unsigned short)u;
}

// ---------------- utility ----------------
__global__ void k_zero_int(int* __restrict__ p, int n) {
    int i = blockIdx.x * blockDim.x + threadIdx.x;
    if (i < n) p[i] = 0;
}

// ---------------- degrees + local position (2 atomics/edge) ----------------
__global__ void k_deg2(const int* __restrict__ src, const int* __restrict__ dst,
                       int* __restrict__ dout, int* __restrict__ din,
                       int* __restrict__ lpos) {
    int e = blockIdx.x * blockDim.x + threadIdx.x;
    if (e < NEDGES) {
        atomicAdd(&dout[src[e]], 1);
        lpos[e] = atomicAdd(&din[dst[e]], 1);
    }
}

// ---------------- block sums of din + fused isqrt of both degree arrays ----------
__global__ void k_blk_sum(const int* __restrict__ din, const int* __restrict__ dout,
                          int* __restrict__ bsum, float* __restrict__ dos,
                          float* __restrict__ dis) {
    __shared__ int red[256];
    int blk = blockIdx.x, tid = threadIdx.x;
    int base = blk * 1024;
    int s = 0;
#pragma unroll
    for (int j = 0; j < 4; ++j) {
        int i = base + tid + j * 256;
        if (i < NNODES) {
            int b = din[i];
            int a = dout[i];
            s += b;
            dos[i] = a > 0 ? 1.0f / sqrtf((float)a) : 0.0f;
            dis[i] = b > 0 ? 1.0f / sqrtf((float)b) : 0.0f;
        }
    }
    red[tid] = s;
    __syncthreads();
    for (int off = 128; off > 0; off >>= 1) {
        if (tid < off) red[tid] += red[tid + off];
        __syncthreads();
    }
    if (tid == 0) bsum[blk] = red[0];
}

__global__ void k_scan_bsum(int* __restrict__ bsum) {
    if (threadIdx.x == 0) {
        int acc = 0;
        for (int i = 0; i < NSCANBLK; ++i) { int v = bsum[i]; bsum[i] = acc; acc += v; }
    }
}

__global__ void k_scan_local(const int* __restrict__ deg, const int* __restrict__ bsum,
                             int* __restrict__ row_ptr) {
    __shared__ int buf[1024];
    int blk = blockIdx.x, tid = threadIdx.x;
    int i = blk * 1024 + tid;
    int v = (i < NNODES) ? deg[i] : 0;
    buf[tid] = v;
    __syncthreads();
    for (int off = 1; off < 1024; off <<= 1) {
        int t = (tid >= off) ? buf[tid - off] : 0;
        __syncthreads();
        buf[tid] += t;
        __syncthreads();
    }
    int inc = buf[tid] + bsum[blk];
    if (i < NNODES) row_ptr[i + 1] = inc;
    if (i == 0) row_ptr[0] = 0;
}

// ---------------- atomic-free edge placement (weight folded out: int records) ------
__global__ void k_place(const int* __restrict__ src, const int* __restrict__ dst,
                        const int* __restrict__ lpos, const int* __restrict__ row_ptr,
                        int* __restrict__ csr_e) {
    int e = blockIdx.x * blockDim.x + threadIdx.x;
    if (e < NEDGES) csr_e[row_ptr[dst[e]] + lpos[e]] = src[e];
}

// ---------------- nf7: pre-scaled node features [N][8] = [nf*w (6), w, 0] ----------
__global__ void k_nf7(const float* __restrict__ nf, const float* __restrict__ dos,
                      float* __restrict__ nf7) {
    int n = blockIdx.x * blockDim.x + threadIdx.x;
    if (n >= NNODES) return;
    float w = dos[n];
    const float* p = nf + (size_t)n * 6;
    float4 lo = {p[0] * w, p[1] * w, p[2] * w, p[3] * w};
    float4 hi = {p[4] * w, p[5] * w, w, 0.f};
    float4* o = (float4*)(nf7 + (size_t)n * 8);
    o[0] = lo; o[1] = hi;
}

// ---------------- fused weight convert: W[K][N] f32 -> Wt[N][K] bf16, 3 mats --------
__global__ void k_wconv3(const float* __restrict__ W2, const float* __restrict__ Wc2,
                         const float* __restrict__ W3, unsigned short* __restrict__ Wt2,
                         unsigned short* __restrict__ Wtc2, unsigned short* __restrict__ Wt3) {
    int idx = blockIdx.x * 256 + threadIdx.x;
    if (idx < 65536) {
        int n = idx >> 8, k = idx & 255;
        Wt2[idx] = f2b(W2[k * 256 + n]);
    } else if (idx < 131072) {
        int j = idx - 65536;
        int n = j >> 8, k = j & 255;
        Wtc2[j] = f2b(Wc2[k * 256 + n]);
    } else if (idx < 163840) {
        int j = idx - 131072;
        int n = j >> 8, k = j & 255;
        Wt3[j] = f2b(W3[k * 128 + n]);
    }
}

// ---------------- M1 = W_emb @ Wc1 (6x256), v1 = b_emb @ Wc1 (256) ----------------
__global__ void k_small_mm(const float* __restrict__ Wemb, const float* __restrict__ bemb,
                           const float* __restrict__ Wc1, float* __restrict__ M1,
                           float* __restrict__ v1) {
    int c = threadIdx.x;
    int bi = blockIdx.x;
    float acc = 0.f;
    if (bi < 6) {
        for (int k = 0; k < HID; ++k) acc = fmaf(Wemb[bi * HID + k], Wc1[k * HID + c], acc);
        M1[bi * HID + c] = acc;
    } else {
        for (int k = 0; k < HID; ++k) acc = fmaf(bemb[k], Wc1[k * HID + c], acc);
        v1[c] = acc;
    }
}

// ---------------- 7-dim edge aggregation (collapsed layer-1 conv, pre-scaled) -------
__global__ void k_agg6(const int* __restrict__ row_ptr, const int* __restrict__ csr_e,
                       const float* __restrict__ nf7, float* __restrict__ t7) {
    int n = blockIdx.x * blockDim.x + threadIdx.x;
    if (n >= NNODES) return;
    float a0 = 0, a1 = 0, a2 = 0, a3 = 0, a4 = 0, a5 = 0, a6 = 0;
    int s = row_ptr[n], e = row_ptr[n + 1];
    int i = s;
    for (; i + 2 <= e; i += 2) {
        const float4* p0 = (const float4*)(nf7 + (size_t)csr_e[i] * 8);
        const float4* p1 = (const float4*)(nf7 + (size_t)csr_e[i + 1] * 8);
        float4 l0 = p0[0], h0 = p0[1], l1 = p1[0], h1 = p1[1];
        a0 += l0.x; a1 += l0.y; a2 += l0.z; a3 += l0.w; a4 += h0.x; a5 += h0.y; a6 += h0.z;
        a0 += l1.x; a1 += l1.y; a2 += l1.z; a3 += l1.w; a4 += h1.x; a5 += h1.y; a6 += h1.z;
    }
    if (i < e) {
        const float4* p0 = (const float4*)(nf7 + (size_t)csr_e[i] * 8);
        float4 l0 = p0[0], h0 = p0[1];
        a0 += l0.x; a1 += l0.y; a2 += l0.z; a3 += l0.w; a4 += h0.x; a5 += h0.y; a6 += h0.z;
    }
    float4* o = (float4*)(t7 + (size_t)n * 8);
    o[0] = make_float4(a0, a1, a2, a3);
    o[1] = make_float4(a4, a5, a6, 0.f);
}

// ---------------- fused layer 1 -> bf16 h_pre1 + fp32 BN partials ----------------
__global__ __launch_bounds__(256) void k_layer1(
    const float* __restrict__ nf, const float* __restrict__ Wemb, const float* __restrict__ bemb,
    const float* __restrict__ M1, const float* __restrict__ v1, const float* __restrict__ bc1,
    const float* __restrict__ t7, const float* __restrict__ dis,
    unsigned short* __restrict__ H, float* __restrict__ psum, float* __restrict__ psq) {
    __shared__ float s_nf[64][6];
    __shared__ float s_t7[64][8];
    __shared__ float s_r[64];
    int blk = blockIdx.x;
    int n0 = blk * 64;
    int tid = threadIdx.x;
    for (int t = tid; t < 384; t += 256) {
        int nl = t / 6, i = t % 6;
        int n = n0 + nl;
        s_nf[nl][i] = (n < NNODES) ? nf[(size_t)n * 6 + i] : 0.f;
    }
    if (tid < 128)   // 64 rows x 8 floats = 128 float4 (t7 allocated to MPAD rows)
        ((float4*)s_t7)[tid] = ((const float4*)(t7 + (size_t)n0 * 8))[tid];
    if (tid < 64) {
        int n = n0 + tid;
        s_r[tid] = (n < NNODES) ? dis[n] : 0.f;
    }
    int c = tid;
    float wc[6], mc[6];
#pragma unroll
    for (int i = 0; i < 6; ++i) { wc[i] = Wemb[i * HID + c]; mc[i] = M1[i * HID + c]; }
    float v1c = v1[c];
    float bsum = bemb[c] + bc1[c];
    __syncthreads();
    float ps = 0.f, pq = 0.f;
    int nmax = min(64, NNODES - n0);
    for (int nl = 0; nl < nmax; ++nl) {
        float nfd = 0.f, td = 0.f;
#pragma unroll
        for (int i = 0; i < 6; ++i) {
            nfd = fmaf(s_nf[nl][i], wc[i], nfd);
            td = fmaf(s_t7[nl][i], mc[i], td);
        }
        float val = nfd + s_r[nl] * (td + s_t7[nl][6] * v1c) + bsum;
        H[(size_t)(n0 + nl) * HID + c] = f2b(val);
        ps += val;
        pq = fmaf(val, val, pq);
    }
    for (int nl = nmax; nl < 64; ++nl) H[(size_t)(n0 + nl) * HID + c] = 0;  // zero pad rows
    psum[blk * HID + c] = ps;
    psq[blk * HID + c] = pq;
}

// ---------------- BN two-stage reduce -> scale/shift ----------------
__global__ void k_bn_part(const float* __restrict__ psum, const float* __restrict__ psq,
                          double* __restrict__ tmp) {
    int c = threadIdx.x;
    int s = blockIdx.x;
    double a = 0.0, b = 0.0;
    for (int bb = s; bb < NROWBLK; bb += REDBLK) {
        a += psum[bb * HID + c];
        b += psq[bb * HID + c];
    }
    tmp[s * HID + c] = a;
    tmp[(REDBLK + s) * HID + c] = b;
}

__global__ void k_bn_final(const double* __restrict__ tmp, const float* __restrict__ g,
                           const float* __restrict__ be, float* __restrict__ scale,
                           float* __restrict__ shift) {
    int c = threadIdx.x;
    double s = 0.0, q = 0.0;
    for (int i = 0; i < REDBLK; ++i) { s += tmp[i * HID + c]; q += tmp[(REDBLK + i) * HID + c]; }
    double mu = s / (double)NNODES;
    double var = q / (double)NNODES - mu * mu;
    if (var < 0.0) var = 0.0;
    double inv = 1.0 / sqrt(var + (double)BN_EPS);
    float sc = (float)((double)g[c] * inv);
    scale[c] = sc;
    shift[c] = be[c] - (float)mu * sc;
}

// ================= bf16 MFMA GEMM, A-panel reused across all column blocks =========
// RS: multiply output rows by rs[row] (folds dout^-1/2 into h2 for the gather pass)
template <int NC, bool ATRANS, bool XEPI, bool PART, bool OUTF32, bool RS>
__global__ __launch_bounds__(256, 2) void k_mgemm(
    const unsigned short* __restrict__ A, const unsigned short* __restrict__ Bt,
    const float* __restrict__ bias,
    const float* __restrict__ scale, const float* __restrict__ shift,
    const float* __restrict__ nf, const float* __restrict__ Wemb, const float* __restrict__ bemb,
    const float* __restrict__ rs,
    unsigned short* __restrict__ Cb, float* __restrict__ Cf,
    float* __restrict__ psum, float* __restrict__ psq) {
    __shared__ unsigned short As[64 * 256];
    __shared__ unsigned short Bs[64 * 256];
    __shared__ float sSc[HID];
    __shared__ float sSh[HID];
    __shared__ float sNf[64][6];
    __shared__ float sXW[6][HID];
    __shared__ float sRs[64];
    __shared__ float redS[2][64];
    __shared__ float redQ[2][64];

    int tid = threadIdx.x;
    int rb = blockIdx.x;
    int row0 = rb * 64;

    if (ATRANS) { sSc[tid] = scale[tid]; sSh[tid] = shift[tid]; }
    if (RS && tid < 64) {
        int n = row0 + tid;
        sRs[tid] = (n < NNODES) ? rs[n] : 0.f;
    }
    if (XEPI) {
        for (int t = tid; t < 6 * NC; t += 256) {
            int i = t / NC, cl = t % NC;
            sXW[i][cl] = Wemb[i * HID + cl];
        }
        if (tid < 64) {
            int n = row0 + tid;
#pragma unroll
            for (int i = 0; i < 6; ++i) sNf[tid][i] = (n < NNODES) ? nf[(size_t)n * 6 + i] : 0.f;
        }
    }
    if (ATRANS) __syncthreads();   // sSc/sSh consumed during A staging

    // ---- stage A tile 64x256 bf16 once ----
#pragma unroll
    for (int i = 0; i < 8; ++i) {
        int g = i * 256 + tid;
        int row = g >> 5, kc = g & 31;
        uint4 v = *(const uint4*)(A + (size_t)(row0 + row) * 256 + kc * 8);
        if (ATRANS) {
            unsigned int w[4] = {v.x, v.y, v.z, v.w};
#pragma unroll
            for (int q = 0; q < 4; ++q) {
                int k0 = kc * 8 + q * 2;
                float f0 = b2f((unsigned short)(w[q] & 0xffffu));
                float f1 = b2f((unsigned short)(w[q] >> 16));
                f0 = fmaxf(fmaf(f0, sSc[k0], sSh[k0]), 0.f);
                f1 = fmaxf(fmaf(f1, sSc[k0 + 1], sSh[k0 + 1]), 0.f);
                w[q] = (unsigned int)f2b(f0) | ((unsigned int)f2b(f1) << 16);
            }
            v.x = w[0]; v.y = w[1]; v.z = w[2]; v.w = w[3];
        }
        int pkc = kc ^ (row & 7);
        *(uint4*)(&As[row * 256 + pkc * 8]) = v;
    }

    int w = tid >> 6, lane = tid & 63;
    int wm = w >> 1, wn = w & 1;            // 2x2 wave grid, each wave 32x32
    int lrow = lane & 15, lk = lane >> 4;

    for (int cb = 0; cb < NC / 64; ++cb) {
        int c0 = cb * 64;
        if (cb) __syncthreads();
        // ---- stage B^T tile 64x256 bf16 ----
#pragma unroll
        for (int i = 0; i < 8; ++i) {
            int g = i * 256 + tid;
            int row = g >> 5, kc = g & 31;
            uint4 v = *(const uint4*)(Bt + (size_t)(c0 + row) * 256 + kc * 8);
            int pkc = kc ^ (row & 7);
            *(uint4*)(&Bs[row * 256 + pkc * 8]) = v;
        }
        __syncthreads();

        f32x4 acc[2][2] = {};
#pragma unroll
        for (int ks = 0; ks < 8; ++ks) {
            bf16x8 af[2], bfr[2];
#pragma unroll
            for (int fm = 0; fm < 2; ++fm) {
                int r = wm * 32 + fm * 16 + lrow;
                int kc = ks * 4 + lk;
                af[fm] = *(const bf16x8*)(&As[r * 256 + (kc ^ (r & 7)) * 8]);
            }
#pragma unroll
            for (int fn = 0; fn < 2; ++fn) {
                int r = wn * 32 + fn * 16 + lrow;
                int kc = ks * 4 + lk;
                bfr[fn] = *(const bf16x8*)(&Bs[r * 256 + (kc ^ (r & 7)) * 8]);
            }
#pragma unroll
            for (int fm = 0; fm < 2; ++fm)
#pragma unroll
                for (int fn = 0; fn < 2; ++fn)
                    acc[fm][fn] = __builtin_amdgcn_mfma_f32_16x16x32_bf16(af[fm], bfr[fn], acc[fm][fn], 0, 0, 0);
        }

        // ---- epilogue (C/D layout: col=lane&15, row=(lane>>4)*4+reg) ----
        float pS[2] = {0.f, 0.f}, pQ[2] = {0.f, 0.f};
#pragma unroll
        for (int fn = 0; fn < 2; ++fn) {
            int cl = wn * 32 + fn * 16 + lrow;
            int gc = c0 + cl;
            float bv = bias[gc];
            if (XEPI) bv += bemb[gc];
#pragma unroll
            for (int fm = 0; fm < 2; ++fm) {
#pragma unroll
                for (int r = 0; r < 4; ++r) {
                    int rl = wm * 32 + fm * 16 + lk * 4 + r;
                    int gr = row0 + rl;
                    float val = acc[fm][fn][r] + bv;
                    if (XEPI) {
#pragma unroll
                        for (int l = 0; l < 6; ++l) val = fmaf(sNf[rl][l], sXW[l][gc], val);
                    }
                    if (RS) val *= sRs[rl];
                    if (gr < NNODES) {
                        if (OUTF32) Cf[(size_t)gr * NC + gc] = val;
                        else        Cb[(size_t)gr * NC + gc] = f2b(val);
                        if (PART) { pS[fn] += val; pQ[fn] = fmaf(val, val, pQ[fn]); }
                    }
                }
            }
        }
        if (PART) {
#pragma unroll
            for (int fn = 0; fn < 2; ++fn) {
                float s = pS[fn], q = pQ[fn];
                s += __shfl_xor(s, 16); s += __shfl_xor(s, 32);
                q += __shfl_xor(q, 16); q += __shfl_xor(q, 32);
                if (lk == 0) {
                    int cl = wn * 32 + fn * 16 + lrow;
                    redS[wm][cl] = s;
                    redQ[wm][cl] = q;
                }
            }
            __syncthreads();
            if (tid < 64) {
                psum[(size_t)rb * HID + c0 + tid] = redS[0][tid] + redS[1][tid];
                psq [(size_t)rb * HID + c0 + tid] = redQ[0][tid] + redQ[1][tid];
            }
        }
    }
}

// ---------------- bf16 conv aggregation: weights pre-folded, plain row sums ---------
#define ADD8(vv) { \
    a[0] += b2f((unsigned short)(vv.x & 0xffffu)); \
    a[1] += b2f((unsigned short)(vv.x >> 16)); \
    a[2] += b2f((unsigned short)(vv.y & 0xffffu)); \
    a[3] += b2f((unsigned short)(vv.y >> 16)); \
    a[4] += b2f((unsigned short)(vv.z & 0xffffu)); \
    a[5] += b2f((unsigned short)(vv.z >> 16)); \
    a[6] += b2f((unsigned short)(vv.w & 0xffffu)); \
    a[7] += b2f((unsigned short)(vv.w >> 16)); }

__global__ __launch_bounds__(256) void k_agg(const int* __restrict__ row_ptr,
                                             const int* __restrict__ csr_e,
                                             const unsigned short* __restrict__ X,
                                             const float* __restrict__ dis,
                                             unsigned short* __restrict__ out) {
    int wid = threadIdx.x >> 6, lane = threadIdx.x & 63;
    int half = lane >> 5, l32 = lane & 31;
    int n = blockIdx.x * 4 + wid;
    if (n >= NNODES) return;
    int s = row_ptr[n], e = row_ptr[n + 1];
    float a[8] = {0.f, 0.f, 0.f, 0.f, 0.f, 0.f, 0.f, 0.f};
    int i = s;
    for (; i + 8 <= e; i += 8) {
        int s0 = csr_e[i + half];
        int s1 = csr_e[i + 2 + half];
        int s2 = csr_e[i + 4 + half];
        int s3 = csr_e[i + 6 + half];
        uint4 v0 = ((const uint4*)(X + (size_t)s0 * HID))[l32];
        uint4 v1 = ((const uint4*)(X + (size_t)s1 * HID))[l32];
        uint4 v2 = ((const uint4*)(X + (size_t)s2 * HID))[l32];
        uint4 v3 = ((const uint4*)(X + (size_t)s3 * HID))[l32];
        ADD8(v0) ADD8(v1) ADD8(v2) ADD8(v3)
    }
    for (; i + 2 <= e; i += 2) {
        int s0 = csr_e[i + half];
        uint4 v0 = ((const uint4*)(X + (size_t)s0 * HID))[l32];
        ADD8(v0)
    }
    if (i < e && half == 0) {       // odd leftover edge: half 0 only
        int s0 = csr_e[i];
        uint4 v0 = ((const uint4*)(X + (size_t)s0 * HID))[l32];
        ADD8(v0)
    }
#pragma unroll
    for (int j = 0; j < 8; ++j) a[j] += __shfl_xor(a[j], 32);
    if (half == 0) {
        float r = dis[n];
        uint4 o;
        o.x = (unsigned)f2b(a[0] * r) | ((unsigned)f2b(a[1] * r) << 16);
        o.y = (unsigned)f2b(a[2] * r) | ((unsigned)f2b(a[3] * r) << 16);
        o.z = (unsigned)f2b(a[4] * r) | ((unsigned)f2b(a[5] * r) << 16);
        o.w = (unsigned)f2b(a[6] * r) | ((unsigned)f2b(a[7] * r) << 16);
        ((uint4*)(out + (size_t)n * HID))[l32] = o;
    }
}

// ---------------- graph mean (sorted graph_ids, binary search) + classifier --------
__global__ __launch_bounds__(128) void k_mean_label(const float* __restrict__ Hout,
                                                    const int* __restrict__ gids,
                                                    const float* __restrict__ Wcls,
                                                    const float* __restrict__ bcls,
                                                    float* __restrict__ lab) {
    int g = blockIdx.x;
    int c = threadIdx.x;
    int lo = 0, hi = NNODES;
    while (lo < hi) { int mid = (lo + hi) >> 1; if (gids[mid] < g) lo = mid + 1; else hi = mid; }
    int s = lo;
    hi = NNODES;
    while (lo < hi) { int mid = (lo + hi) >> 1; if (gids[mid] < g + 1) lo = mid + 1; else hi = mid; }
    int e = lo;
    float acc = 0.f;
    for (int n = s; n < e; ++n) acc += Hout[(size_t)n * OUTD + c];
    int cnt = e - s;
    float y = acc / (float)max(cnt, 1);
    __shared__ float ys[OUTD];
    ys[c] = y;
    __syncthreads();
    if (c < NCLS) {
        float a = bcls[c];
        for (int k = 0; k < OUTD; ++k) a = fmaf(ys[k], Wcls[k * NCLS + c], a);
        lab[(size_t)g * NCLS + c] = a;
    }
}

// ---------------- host ----------------
extern "C" void kernel_launch(void* const* d_in, const int* in_sizes, int n_in,
                              void* d_out, int out_size, void* d_ws, size_t ws_size,
                              hipStream_t stream) {
    const float* nf   = (const float*)d_in[0];
    const int*   src  = (const int*)d_in[1];
    const int*   dst  = (const int*)d_in[2];
    const int*   gids = (const int*)d_in[3];
    const float* Wemb = (const float*)d_in[4];
    const float* bemb = (const float*)d_in[5];
    const float* Wc1  = (const float*)d_in[6];
    const float* bc1  = (const float*)d_in[7];
    const float* g1   = (const float*)d_in[8];
    const float* be1  = (const float*)d_in[9];
    const float* W2   = (const float*)d_in[10];
    const float* b2   = (const float*)d_in[11];
    const float* Wc2  = (const float*)d_in[12];
    const float* bc2  = (const float*)d_in[13];
    const float* g2   = (const float*)d_in[14];
    const float* be2  = (const float*)d_in[15];
    const float* W3   = (const float*)d_in[16];
    const float* b3   = (const float*)d_in[17];
    const float* Wcls = (const float*)d_in[18];
    const float* bcls = (const float*)d_in[19];

    float* out_h   = (float*)d_out;                 // [N, 128] fp32
    float* out_lab = out_h + (size_t)NNODES * OUTD; // [G, 60]

    // workspace bump allocator (floats, 256B granularity)
    float* ws = (float*)d_ws;
    size_t off = 0;
    auto take = [&](size_t n) { float* p = ws + off; off += (n + 63) & ~(size_t)63; return p; };
    unsigned short* actA = (unsigned short*)take((size_t)MPAD * HID / 2);  // bf16 [MPAD][256]
    unsigned short* actB = (unsigned short*)take((size_t)MPAD * HID / 2);  // bf16 [MPAD][256]
    unsigned short* Wt2  = (unsigned short*)take(HID * HID / 2);
    unsigned short* Wtc2 = (unsigned short*)take(HID * HID / 2);
    unsigned short* Wt3  = (unsigned short*)take(OUTD * HID / 2);
    int*   deg_out = (int*)take(NNODES);
    int*   deg_in  = (int*)take(NNODES);
    float* dout_is = take(NNODES);
    float* din_is  = take(NNODES);
    int*   row_ptr = (int*)take(NNODES + 1);
    int*   lpos    = (int*)take(NEDGES);
    int*   csr_e   = (int*)take(NEDGES);
    float* nf7     = take((size_t)NNODES * 8);
    float* t7      = take((size_t)MPAD * 8);
    float* M1      = take(6 * HID);
    float* v1      = take(HID);
    float* psum    = take((size_t)NROWBLK * HID);
    float* psq     = take((size_t)NROWBLK * HID);
    float* scale1  = take(HID);
    float* shift1  = take(HID);
    float* scale2  = take(HID);
    float* shift2  = take(HID);
    int*   bsum    = (int*)take(128);
    double* bn_tmp = (double*)take(2 * 2 * REDBLK * HID);

    // 1. zero degree arrays (deg_out/deg_in contiguous)
    k_zero_int<<<(2 * 100032 + 255) / 256, 256, 0, stream>>>(deg_out, 2 * 100032);
    // 2. degrees + local positions (2 atomics/edge)
    k_deg2<<<(NEDGES + 255) / 256, 256, 0, stream>>>(src, dst, deg_out, deg_in, lpos);
    // 3. block sums + fused isqrt
    k_blk_sum<<<NSCANBLK, 256, 0, stream>>>(deg_in, deg_out, bsum, dout_is, din_is);
    k_scan_bsum<<<1, 64, 0, stream>>>(bsum);
    k_scan_local<<<NSCANBLK, 1024, 0, stream>>>(deg_in, bsum, row_ptr);
    // 4. atomic-free placement (int records)
    k_place<<<(NEDGES + 255) / 256, 256, 0, stream>>>(src, dst, lpos, row_ptr, csr_e);
    // 5. pre-scaled node features + weight conversion + M1/v1
    k_nf7<<<(NNODES + 255) / 256, 256, 0, stream>>>(nf, dout_is, nf7);
    k_wconv3<<<640, 256, 0, stream>>>(W2, Wc2, W3, Wt2, Wtc2, Wt3);
    k_small_mm<<<7, 256, 0, stream>>>(Wemb, bemb, Wc1, M1, v1);
    // 6. 7-dim aggregation (weights pre-folded)
    k_agg6<<<(NNODES + 255) / 256, 256, 0, stream>>>(row_ptr, csr_e, nf7, t7);
    // 7. fused layer 1 -> actA (h_pre1 bf16) + BN1 partials
    k_layer1<<<NROWBLK, 256, 0, stream>>>(nf, Wemb, bemb, M1, v1, bc1, t7, din_is,
                                          actA, psum, psq);
    // 8. BN1 scale/shift
    k_bn_part<<<REDBLK, 256, 0, stream>>>(psum, psq, bn_tmp);
    k_bn_final<<<1, 256, 0, stream>>>(bn_tmp, g1, be1, scale1, shift1);
    // 9. h2 = (relu(bn1(h_pre1)) @ W2 + b2) * dout^-1/2[row] -> actB (bf16)
    k_mgemm<HID, true, false, false, false, true><<<NROWBLK, 256, 0, stream>>>(
        actA, Wt2, b2, scale1, shift1, nullptr, nullptr, nullptr, dout_is,
        actB, nullptr, nullptr, nullptr);
    // 10. A2 = dis * row-sum gather of actB -> actA (bf16)
    k_agg<<<NNODES / 4, 256, 0, stream>>>(row_ptr, csr_e, actB, din_is, actA);
    // 11. h_pre2 = x + A2 @ Wc2 + bc2 -> actB (bf16) + BN2 partials
    k_mgemm<HID, false, true, true, false, false><<<NROWBLK, 256, 0, stream>>>(
        actA, Wtc2, bc2, nullptr, nullptr, nf, Wemb, bemb, nullptr,
        actB, nullptr, psum, psq);
    // 12. BN2 scale/shift
    k_bn_part<<<REDBLK, 256, 0, stream>>>(psum, psq, bn_tmp);
    k_bn_final<<<1, 256, 0, stream>>>(bn_tmp, g2, be2, scale2, shift2);
    // 13. h_out = relu(bn2(h_pre2)) @ W3 + b3 -> d_out fp32
    k_mgemm<OUTD, true, false, false, true, false><<<NROWBLK, 256, 0, stream>>>(
        actB, Wt3, b3, scale2, shift2, nullptr, nullptr, nullptr, nullptr,
        nullptr, out_h, nullptr, nullptr);
    // 14. graph mean + classifier
    k_mean_label<<<NGRAPHS, OUTD, 0, stream>>>(out_h, gids, Wcls, bcls, out_lab);
}